// Round 1
// baseline (1371.463 us; speedup 1.0000x reference)
//
#include <hip/hip_runtime.h>
#include <math.h>

#define B_   2
#define S_   2048
#define D_   1024
#define H_   16
#define KH_  4
#define DK_  64
#define REP_ 4

// ---------------------------------------------------------------------------
// Tiled fp32 GEMM: C[M,N] = A[M,K] @ W[K,N] + bias[N]
// mode 0: out[m*N + n]                      (plain row-major)
// mode 1: out[((b*NH + h)*S + s)*DK + d]    (head scatter, NH = N/64)
// BM=BN=64, BK=16, 256 threads, 4x4 micro-tile per thread.
// ---------------------------------------------------------------------------
__global__ __launch_bounds__(256) void gemm_kernel(
    const float* __restrict__ A, const float* __restrict__ W,
    const float* __restrict__ bias, float* __restrict__ out,
    int M, int N, int K, int mode)
{
    __shared__ float As[16][68];   // [kk][m], stride 68 keeps float4 alignment
    __shared__ float Bs[16][64];   // [kk][n]

    const int t  = threadIdx.x;
    const int tx = t & 15;         // -> 4 output cols
    const int ty = t >> 4;         // -> 4 output rows
    const int m0 = blockIdx.y * 64;
    const int n0 = blockIdx.x * 64;

    const int am  = t >> 2;        // 0..63  (A row within tile)
    const int ak4 = (t & 3) * 4;   // 0,4,8,12 (A k-offset, float4)
    const int bk  = t >> 4;        // 0..15  (B k row)
    const int bn4 = (t & 15) * 4;  // 0..60  (B n-offset, float4)

    float acc[4][4] = {};

    for (int k0 = 0; k0 < K; k0 += 16) {
        float4 av = *(const float4*)&A[(long)(m0 + am) * K + k0 + ak4];
        float4 bv = *(const float4*)&W[(long)(k0 + bk) * N + n0 + bn4];
        __syncthreads();           // protect LDS from previous iteration reads
        As[ak4 + 0][am] = av.x;
        As[ak4 + 1][am] = av.y;
        As[ak4 + 2][am] = av.z;
        As[ak4 + 3][am] = av.w;
        *(float4*)&Bs[bk][bn4] = bv;
        __syncthreads();
        #pragma unroll
        for (int kk = 0; kk < 16; ++kk) {
            float4 a = *(const float4*)&As[kk][ty * 4];
            float4 b = *(const float4*)&Bs[kk][tx * 4];
            acc[0][0] = fmaf(a.x, b.x, acc[0][0]);
            acc[0][1] = fmaf(a.x, b.y, acc[0][1]);
            acc[0][2] = fmaf(a.x, b.z, acc[0][2]);
            acc[0][3] = fmaf(a.x, b.w, acc[0][3]);
            acc[1][0] = fmaf(a.y, b.x, acc[1][0]);
            acc[1][1] = fmaf(a.y, b.y, acc[1][1]);
            acc[1][2] = fmaf(a.y, b.z, acc[1][2]);
            acc[1][3] = fmaf(a.y, b.w, acc[1][3]);
            acc[2][0] = fmaf(a.z, b.x, acc[2][0]);
            acc[2][1] = fmaf(a.z, b.y, acc[2][1]);
            acc[2][2] = fmaf(a.z, b.z, acc[2][2]);
            acc[2][3] = fmaf(a.z, b.w, acc[2][3]);
            acc[3][0] = fmaf(a.w, b.x, acc[3][0]);
            acc[3][1] = fmaf(a.w, b.y, acc[3][1]);
            acc[3][2] = fmaf(a.w, b.z, acc[3][2]);
            acc[3][3] = fmaf(a.w, b.w, acc[3][3]);
        }
    }

    const int NH = N >> 6;
    #pragma unroll
    for (int i = 0; i < 4; ++i) {
        const int gm = m0 + ty * 4 + i;
        const int bb = gm >> 11;          // / S_
        const int s  = gm & (S_ - 1);
        #pragma unroll
        for (int j = 0; j < 4; ++j) {
            const int gn = n0 + tx * 4 + j;
            const float val = acc[i][j] + bias[gn];
            if (mode == 0) {
                out[(long)gm * N + gn] = val;
            } else {
                const int h = gn >> 6, d = gn & 63;
                out[(((long)(bb * NH + h)) * S_ + s) * DK_ + d] = val;
            }
        }
    }
}

// ---------------------------------------------------------------------------
// RoPE in-place on (rows, DK) with s = row % S. Pairs (d, d+32), d < 32.
// ---------------------------------------------------------------------------
__global__ __launch_bounds__(256) void rope_kernel(float* __restrict__ p, int total)
{
    const int idx = blockIdx.x * 256 + threadIdx.x;
    if (idx >= total) return;
    const int r = idx >> 5;
    const int d = idx & 31;
    const int s = r & (S_ - 1);
    float* row = p + (long)r * DK_;
    const float x1 = row[d];
    const float x2 = row[d + 32];
    // theta = 10000^(-d/32)
    const float theta = expf(-(float)d * (9.210340371976184f / 32.0f)); // ln(10000)
    const float f = (float)s * theta;
    const float c = cosf(f), sn = sinf(f);
    row[d]      = x1 * c - x2 * sn;
    row[d + 32] = x2 * c + x1 * sn;
}

// ---------------------------------------------------------------------------
// Causal flash attention, fp32, online softmax.
// Block = 512 threads (8 waves), one block handles 8 wave-slots of one (b,h).
// Each query row is owned by a lane PAIR (d-split into halves of 32) so we
// get 2 waves/SIMD. Wave->row-block table pairs heavy+light causal work on
// the same SIMD (sums to a constant).
// K/V tiles of 64 keys staged in LDS (32 KB).
// ---------------------------------------------------------------------------
__global__ __launch_bounds__(512) void attn_kernel(
    const float* __restrict__ qt,  // (B,H,S,DK)
    const float* __restrict__ kt,  // (B,KH,S,DK)
    const float* __restrict__ vt,  // (B,KH,S,DK)
    float* __restrict__ ot)        // (B,S,H,DK)
{
    __shared__ float Ks[64][64];
    __shared__ float Vs[64][64];

    const int tid = threadIdx.x;
    const int bx  = blockIdx.x;
    const int j   = bx & 7;          // block index within (b,h)
    const int h   = (bx >> 3) & (H_ - 1);
    const int b   = bx >> 7;
    const int kh  = h >> 2;          // GQA: h / REP

    const int w    = tid >> 6;       // wave 0..7
    const int lane = tid & 63;
    const int rw   = lane >> 1;      // row within wave, 0..31
    const int half = lane & 1;       // which 32-wide half of DK

    // Row-block table: SIMD pairs (w, w+4) sum to 63 -> balanced causal work.
    int Wv;
    switch (w) {
        case 0: Wv = j;       break;
        case 1: Wv = 15 - j;  break;
        case 2: Wv = 16 + j;  break;
        case 3: Wv = 31 - j;  break;
        case 4: Wv = 63 - j;  break;
        case 5: Wv = 48 + j;  break;
        case 6: Wv = 47 - j;  break;
        default: Wv = 32 + j; break;
    }
    const int qrow  = Wv * 32 + rw;   // 0..2047
    const int dbase = half * 32;

    const float* qp = qt + (((long)(b * H_ + h) * S_ + qrow) * DK_) + dbase;
    float4 q4[8];
    #pragma unroll
    for (int u = 0; u < 8; ++u) q4[u] = *(const float4*)&qp[u * 4];

    float4 o4[8] = {};
    float m_run = -INFINITY, l_run = 0.0f;

    const int maxW      = 63 - j;                    // max Wv in this block
    const int num_tiles = ((maxW * 32 + 31) >> 6) + 1;
    const int my_last   = Wv * 32 + 31;

    const float* kbase = kt + ((long)(b * KH_ + kh) * S_) * DK_;
    const float* vbase = vt + ((long)(b * KH_ + kh) * S_) * DK_;

    for (int t = 0; t < num_tiles; ++t) {
        __syncthreads();
        {   // stage 64 keys x 64 dims of K and V: 1024 float4 each, 512 threads
            const float4* srcK = (const float4*)(kbase + (long)t * 64 * DK_);
            const float4* srcV = (const float4*)(vbase + (long)t * 64 * DK_);
            float4* dstK = (float4*)&Ks[0][0];
            float4* dstV = (float4*)&Vs[0][0];
            #pragma unroll
            for (int i = 0; i < 2; ++i) {
                dstK[tid + i * 512] = srcK[tid + i * 512];
                dstV[tid + i * 512] = srcV[tid + i * 512];
            }
        }
        __syncthreads();

        if (t * 64 <= my_last) {                       // wave-uniform
            const int kmax   = min(64, my_last - t * 64 + 1);  // wave-uniform
            const int base_k = t * 64;
            for (int kk = 0; kk < kmax; ++kk) {
                const float4* krow = (const float4*)&Ks[kk][dbase];
                float ax = 0.f, ay = 0.f, az = 0.f, aw = 0.f;
                #pragma unroll
                for (int u = 0; u < 8; ++u) {
                    float4 kv = krow[u];
                    ax = fmaf(q4[u].x, kv.x, ax);
                    ay = fmaf(q4[u].y, kv.y, ay);
                    az = fmaf(q4[u].z, kv.z, az);
                    aw = fmaf(q4[u].w, kv.w, aw);
                }
                float sc = (ax + ay) + (az + aw);
                sc += __shfl_xor(sc, 1);               // combine the two halves
                sc *= 0.125f;                          // 1/sqrt(64)
                if (base_k + kk <= qrow) {
                    const float mn = fmaxf(m_run, sc);
                    const float c  = expf(m_run - mn); // 0 on first key (m=-inf)
                    const float p  = expf(sc - mn);
                    l_run = l_run * c + p;
                    m_run = mn;
                    const float4* vrow = (const float4*)&Vs[kk][dbase];
                    #pragma unroll
                    for (int u = 0; u < 8; ++u) {
                        float4 vv = vrow[u];
                        o4[u].x = fmaf(o4[u].x, c, p * vv.x);
                        o4[u].y = fmaf(o4[u].y, c, p * vv.y);
                        o4[u].z = fmaf(o4[u].z, c, p * vv.z);
                        o4[u].w = fmaf(o4[u].w, c, p * vv.w);
                    }
                }
            }
        }
    }

    const float inv = 1.0f / l_run;
    float* op = ot + (((long)(b * S_ + qrow) * H_ + h) * DK_) + dbase;
    #pragma unroll
    for (int u = 0; u < 8; ++u) {
        float4 v = o4[u];
        v.x *= inv; v.y *= inv; v.z *= inv; v.w *= inv;
        *(float4*)&op[u * 4] = v;
    }
}

// ---------------------------------------------------------------------------
extern "C" void kernel_launch(void* const* d_in, const int* in_sizes, int n_in,
                              void* d_out, int out_size, void* d_ws, size_t ws_size,
                              hipStream_t stream)
{
    const float* x  = (const float*)d_in[0];
    // d_in[1] = mask (int32, causal tril) -- implemented implicitly
    const float* Wq = (const float*)d_in[2];
    const float* bq = (const float*)d_in[3];
    const float* Wk = (const float*)d_in[4];
    const float* bk = (const float*)d_in[5];
    const float* Wv = (const float*)d_in[6];
    const float* bv = (const float*)d_in[7];
    const float* Wo = (const float*)d_in[8];
    const float* bo = (const float*)d_in[9];
    float* out = (float*)d_out;

    // Workspace layout (floats): q_t | k_t | v_t | attn_o   (40 MB total)
    float* ws = (float*)d_ws;
    float* qt = ws;                       // B*H*S*DK   = 4194304
    float* kt = qt + 4194304;             // B*KH*S*DK  = 1048576
    float* vt = kt + 1048576;             // B*KH*S*DK  = 1048576
    float* ot = vt + 1048576;             // B*S*H*DK   = 4194304

    const int M = B_ * S_;                // 4096

    // QKV projections (head-scatter epilogue -> (B,heads,S,DK) layouts)
    gemm_kernel<<<dim3(1024 / 64, M / 64), 256, 0, stream>>>(x, Wq, bq, qt, M, 1024, D_, 1);
    gemm_kernel<<<dim3(256 / 64,  M / 64), 256, 0, stream>>>(x, Wk, bk, kt, M, 256,  D_, 1);
    gemm_kernel<<<dim3(256 / 64,  M / 64), 256, 0, stream>>>(x, Wv, bv, vt, M, 256,  D_, 1);

    // RoPE in-place on q and k
    rope_kernel<<<(B_ * H_ * S_ * 32 + 255) / 256, 256, 0, stream>>>(qt, B_ * H_ * S_ * 32);
    rope_kernel<<<(B_ * KH_ * S_ * 32 + 255) / 256, 256, 0, stream>>>(kt, B_ * KH_ * S_ * 32);

    // Causal flash attention -> (B,S,H*DK)
    attn_kernel<<<B_ * H_ * 8, 512, 0, stream>>>(qt, kt, vt, ot);

    // Output projection (plain epilogue)
    gemm_kernel<<<dim3(1024 / 64, M / 64), 256, 0, stream>>>(ot, Wo, bo, out, M, 1024, D_, 0);
}

// Round 2
// 610.805 us; speedup vs baseline: 2.2453x; 2.2453x over previous
//
#include <hip/hip_runtime.h>
#include <math.h>

#define B_   2
#define S_   2048
#define D_   1024
#define H_   16
#define KH_  4
#define DK_  64

using bf16x8 = __attribute__((ext_vector_type(8))) short;
using f32x4  = __attribute__((ext_vector_type(4))) float;
using u32x4  = __attribute__((ext_vector_type(4))) unsigned int;

__device__ inline unsigned short f2bf(float f) {
    unsigned u = __float_as_uint(f);
    u += 0x7FFFu + ((u >> 16) & 1u);          // RNE
    return (unsigned short)(u >> 16);
}

// ---------------------------------------------------------------------------
// Tiled fp32 GEMM: C[M,N] = A[M,K] @ W[K,N] + bias[N]
// mode 0: out[m*N + n]; mode 1: head scatter fp32 (B,NH,S,DK)
// ---------------------------------------------------------------------------
__global__ __launch_bounds__(256) void gemm_kernel(
    const float* __restrict__ A, const float* __restrict__ W,
    const float* __restrict__ bias, float* __restrict__ out,
    int M, int N, int K, int mode)
{
    __shared__ float As[16][68];
    __shared__ float Bs[16][64];

    const int t  = threadIdx.x;
    const int tx = t & 15;
    const int ty = t >> 4;
    const int m0 = blockIdx.y * 64;
    const int n0 = blockIdx.x * 64;

    const int am  = t >> 2;
    const int ak4 = (t & 3) * 4;
    const int bk  = t >> 4;
    const int bn4 = (t & 15) * 4;

    float acc[4][4] = {};

    for (int k0 = 0; k0 < K; k0 += 16) {
        float4 av = *(const float4*)&A[(long)(m0 + am) * K + k0 + ak4];
        float4 bv = *(const float4*)&W[(long)(k0 + bk) * N + n0 + bn4];
        __syncthreads();
        As[ak4 + 0][am] = av.x;
        As[ak4 + 1][am] = av.y;
        As[ak4 + 2][am] = av.z;
        As[ak4 + 3][am] = av.w;
        *(float4*)&Bs[bk][bn4] = bv;
        __syncthreads();
        #pragma unroll
        for (int kk = 0; kk < 16; ++kk) {
            float4 a = *(const float4*)&As[kk][ty * 4];
            float4 b = *(const float4*)&Bs[kk][tx * 4];
            acc[0][0] = fmaf(a.x, b.x, acc[0][0]);
            acc[0][1] = fmaf(a.x, b.y, acc[0][1]);
            acc[0][2] = fmaf(a.x, b.z, acc[0][2]);
            acc[0][3] = fmaf(a.x, b.w, acc[0][3]);
            acc[1][0] = fmaf(a.y, b.x, acc[1][0]);
            acc[1][1] = fmaf(a.y, b.y, acc[1][1]);
            acc[1][2] = fmaf(a.y, b.z, acc[1][2]);
            acc[1][3] = fmaf(a.y, b.w, acc[1][3]);
            acc[2][0] = fmaf(a.z, b.x, acc[2][0]);
            acc[2][1] = fmaf(a.z, b.y, acc[2][1]);
            acc[2][2] = fmaf(a.z, b.z, acc[2][2]);
            acc[2][3] = fmaf(a.z, b.w, acc[2][3]);
            acc[3][0] = fmaf(a.w, b.x, acc[3][0]);
            acc[3][1] = fmaf(a.w, b.y, acc[3][1]);
            acc[3][2] = fmaf(a.w, b.z, acc[3][2]);
            acc[3][3] = fmaf(a.w, b.w, acc[3][3]);
        }
    }

    const int NH = N >> 6;
    #pragma unroll
    for (int i = 0; i < 4; ++i) {
        const int gm = m0 + ty * 4 + i;
        const int bb = gm >> 11;
        const int s  = gm & (S_ - 1);
        #pragma unroll
        for (int j = 0; j < 4; ++j) {
            const int gn = n0 + tx * 4 + j;
            const float val = acc[i][j] + bias[gn];
            if (mode == 0) {
                out[(long)gm * N + gn] = val;
            } else {
                const int h = gn >> 6, d = gn & 63;
                out[(((long)(bb * NH + h)) * S_ + s) * DK_ + d] = val;
            }
        }
    }
}

// ---------------------------------------------------------------------------
// RoPE fp32 -> bf16: in (B,NH,S,DK) fp32, out same layout bf16.
// ---------------------------------------------------------------------------
__global__ __launch_bounds__(256) void rope_cast_kernel(
    const float* __restrict__ in, unsigned short* __restrict__ out, int total)
{
    const int idx = blockIdx.x * 256 + threadIdx.x;
    if (idx >= total) return;
    const int r = idx >> 5;
    const int d = idx & 31;
    const int s = r & (S_ - 1);
    const float* row = in + (long)r * DK_;
    const float x1 = row[d];
    const float x2 = row[d + 32];
    const float theta = expf(-(float)d * (9.210340371976184f / 32.0f));
    const float f = (float)s * theta;
    const float c = cosf(f), sn = sinf(f);
    out[(long)r * DK_ + d]      = f2bf(x1 * c - x2 * sn);
    out[(long)r * DK_ + d + 32] = f2bf(x2 * c + x1 * sn);
}

// ---------------------------------------------------------------------------
// V transpose + cast: fp32 (B,KH,S,DK) -> bf16 (B,KH,DK,S)
// ---------------------------------------------------------------------------
__global__ __launch_bounds__(256) void transpose_v_kernel(
    const float* __restrict__ in, unsigned short* __restrict__ out)
{
    __shared__ float T[64][65];
    const int bx  = blockIdx.x;
    const int bkh = bx >> 5;            // 0..7
    const int s0  = (bx & 31) * 64;
    const int t   = threadIdx.x;

    {   // load 64 s-rows x 64 dims
        const int s  = t >> 2;
        const int dq = (t & 3) * 16;
        const float* src = in + ((long)bkh * S_ + s0 + s) * DK_ + dq;
        #pragma unroll
        for (int i = 0; i < 4; ++i) {
            f32x4 v = *(const f32x4*)(src + i * 4);
            T[s][dq + i * 4 + 0] = v[0];
            T[s][dq + i * 4 + 1] = v[1];
            T[s][dq + i * 4 + 2] = v[2];
            T[s][dq + i * 4 + 3] = v[3];
        }
    }
    __syncthreads();
    {   // write 64 d-rows x 64 s
        const int d  = t >> 2;
        const int sq = (t & 3) * 16;
        bf16x8 p0, p1;
        #pragma unroll
        for (int i = 0; i < 8; ++i) {
            p0[i] = (short)f2bf(T[sq + i][d]);
            p1[i] = (short)f2bf(T[sq + 8 + i][d]);
        }
        unsigned short* dst = out + ((long)bkh * DK_ + d) * S_ + s0 + sq;
        *(bf16x8*)dst       = p0;
        *(bf16x8*)(dst + 8) = p1;
    }
}

// ---------------------------------------------------------------------------
// bf16 MFMA causal flash attention.
// Block = 256 thr = 4 waves. Wave handles 16 queries; block = 64-query tile.
// K/V tiles of 64 keys in LDS; P round-trips per-wave LDS (m120 pattern).
// mfma_f32_16x16x32_bf16: A[m=lane&15][k=quad*8+j]; C col=lane&15,
// row=quad*4+reg. Score-C and O-C share the row mapping -> in-lane rescale.
// qtile swizzle pairs j with 31-j in adjacent blocks (causal balance).
// ---------------------------------------------------------------------------
__global__ __launch_bounds__(256) void attn_mfma_kernel(
    const unsigned short* __restrict__ qb,   // (B,H,S,DK) bf16, roped
    const unsigned short* __restrict__ kbf,  // (B,KH,S,DK) bf16, roped
    const unsigned short* __restrict__ vT,   // (B,KH,DK,S) bf16
    float* __restrict__ ot)                  // (B,S,H,DK) fp32
{
    __shared__ unsigned short Ks[64][72];    // [key][dim], pad 8
    __shared__ unsigned short Vs[64][72];    // [dim][key], pad 8
    __shared__ unsigned short Ps[4][16][72]; // per-wave P, pad 8

    const int tid = threadIdx.x;
    const int bx  = blockIdx.x;
    const int bh  = bx >> 5;
    const int b   = bh >> 4, h = bh & 15;
    const int kh  = h >> 2;
    const int rr  = bx & 31;
    const int qtile = (rr & 1) ? 31 - (rr >> 1) : (rr >> 1);
    const int q0  = qtile * 64;

    const int wv   = tid >> 6;
    const int lane = tid & 63;
    const int n    = lane & 15;
    const int quad = lane >> 4;

    // Q fragments (A-operand): row q0 + wv*16 + n, k = quad*8+j (+32)
    const unsigned short* qp = qb + ((long)(b * H_ + h) * S_ + q0 + wv * 16 + n) * DK_;
    const bf16x8 qa0 = *(const bf16x8*)(qp + quad * 8);
    const bf16x8 qa1 = *(const bf16x8*)(qp + 32 + quad * 8);

    f32x4 O[4];
    #pragma unroll
    for (int dt = 0; dt < 4; ++dt) O[dt] = 0.0f;
    float mrun[4] = {-INFINITY, -INFINITY, -INFINITY, -INFINITY};
    float lrun[4] = {0.f, 0.f, 0.f, 0.f};

    const unsigned short* kbase = kbf + (long)(b * KH_ + kh) * S_ * DK_;
    const unsigned short* vbase = vT  + (long)(b * KH_ + kh) * DK_ * S_;

    const int ntiles = qtile + 1;
    const int rowg0  = q0 + wv * 16 + quad * 4;

    for (int t = 0; t < ntiles; ++t) {
        const int kb = t * 64;
        __syncthreads();                      // all waves done with prev tile
        #pragma unroll
        for (int i = 0; i < 2; ++i) {         // stage K tile + V^T tile
            const int flat = tid + i * 256;   // 512 chunks of 8 bf16
            const int row = flat >> 3, c8 = (flat & 7) * 8;
            *(u32x4*)&Ks[row][c8] = *(const u32x4*)(kbase + (long)(kb + row) * DK_ + c8);
            *(u32x4*)&Vs[row][c8] = *(const u32x4*)(vbase + (long)row * S_ + kb + c8);
        }
        __syncthreads();

        // ---- QK^T: 16 queries x 64 keys ----
        f32x4 sc[4];
        #pragma unroll
        for (int ct = 0; ct < 4; ++ct) {
            const bf16x8 b0 = *(const bf16x8*)&Ks[ct * 16 + n][quad * 8];
            const bf16x8 b1 = *(const bf16x8*)&Ks[ct * 16 + n][32 + quad * 8];
            f32x4 c = 0.0f;
            c = __builtin_amdgcn_mfma_f32_16x16x32_bf16(qa0, b0, c, 0, 0, 0);
            c = __builtin_amdgcn_mfma_f32_16x16x32_bf16(qa1, b1, c, 0, 0, 0);
            sc[ct] = c;
        }

        // ---- mask + scale + online softmax (stats in-register) ----
        float cr[4];
        #pragma unroll
        for (int r = 0; r < 4; ++r) {
            float mx = -INFINITY;
            #pragma unroll
            for (int ct = 0; ct < 4; ++ct) {
                const int col = kb + ct * 16 + n;
                float s = sc[ct][r] * 0.125f;          // 1/sqrt(64)
                s = (col <= rowg0 + r) ? s : -INFINITY;
                sc[ct][r] = s;
                mx = fmaxf(mx, s);
            }
            mx = fmaxf(mx, __shfl_xor(mx, 1));
            mx = fmaxf(mx, __shfl_xor(mx, 2));
            mx = fmaxf(mx, __shfl_xor(mx, 4));
            mx = fmaxf(mx, __shfl_xor(mx, 8));
            const float mn = fmaxf(mrun[r], mx);       // finite after tile 0
            const float c_ = expf(mrun[r] - mn);       // 0 on first tile
            float rs = 0.f;
            #pragma unroll
            for (int ct = 0; ct < 4; ++ct) {
                const float p = expf(sc[ct][r] - mn);  // -inf -> 0
                sc[ct][r] = p;
                rs += p;
            }
            rs += __shfl_xor(rs, 1);
            rs += __shfl_xor(rs, 2);
            rs += __shfl_xor(rs, 4);
            rs += __shfl_xor(rs, 8);
            lrun[r] = lrun[r] * c_ + rs;
            mrun[r] = mn;
            cr[r] = c_;
        }
        #pragma unroll
        for (int dt = 0; dt < 4; ++dt)
            #pragma unroll
            for (int r = 0; r < 4; ++r) O[dt][r] *= cr[r];

        // ---- P -> LDS (C-layout) -> A-frags ----
        #pragma unroll
        for (int ct = 0; ct < 4; ++ct)
            #pragma unroll
            for (int r = 0; r < 4; ++r)
                Ps[wv][quad * 4 + r][ct * 16 + n] = f2bf(sc[ct][r]);
        const bf16x8 pa0 = *(const bf16x8*)&Ps[wv][n][quad * 8];
        const bf16x8 pa1 = *(const bf16x8*)&Ps[wv][n][32 + quad * 8];

        // ---- PV: O[16q][64d] ----
        #pragma unroll
        for (int dt = 0; dt < 4; ++dt) {
            const bf16x8 v0 = *(const bf16x8*)&Vs[dt * 16 + n][quad * 8];
            const bf16x8 v1 = *(const bf16x8*)&Vs[dt * 16 + n][32 + quad * 8];
            O[dt] = __builtin_amdgcn_mfma_f32_16x16x32_bf16(pa0, v0, O[dt], 0, 0, 0);
            O[dt] = __builtin_amdgcn_mfma_f32_16x16x32_bf16(pa1, v1, O[dt], 0, 0, 0);
        }
    }

    // epilogue: normalize, store fp32 (B,S,H,DK)
    #pragma unroll
    for (int r = 0; r < 4; ++r) {
        const float inv = 1.0f / lrun[r];
        float* op = ot + ((long)(b * S_ + rowg0 + r) * H_ + h) * DK_;
        #pragma unroll
        for (int dt = 0; dt < 4; ++dt)
            op[dt * 16 + n] = O[dt][r] * inv;
    }
}

// ---------------------------------------------------------------------------
extern "C" void kernel_launch(void* const* d_in, const int* in_sizes, int n_in,
                              void* d_out, int out_size, void* d_ws, size_t ws_size,
                              hipStream_t stream)
{
    const float* x  = (const float*)d_in[0];
    const float* Wq = (const float*)d_in[2];
    const float* bq = (const float*)d_in[3];
    const float* Wk = (const float*)d_in[4];
    const float* bk = (const float*)d_in[5];
    const float* Wv = (const float*)d_in[6];
    const float* bv = (const float*)d_in[7];
    const float* Wo = (const float*)d_in[8];
    const float* bo = (const float*)d_in[9];
    float* out = (float*)d_out;

    // Workspace: qt(16M) kt(4M) vt(4M) | qb(8M) kb(2M) vT(2M) = 36 MB.
    // ot aliases qt (qt is dead after rope_cast_q; attn reads qb only).
    float* ws = (float*)d_ws;
    float* qt = ws;                          // 4194304 f
    float* kt = qt + 4194304;                // 1048576 f
    float* vt = kt + 1048576;                // 1048576 f
    float* ot = qt;                          // alias
    unsigned short* qb  = (unsigned short*)(vt + 1048576);  // 4194304 us
    unsigned short* kbq = qb + 4194304;                     // 1048576 us
    unsigned short* vT  = kbq + 1048576;                    // 1048576 us

    const int M = B_ * S_;                   // 4096

    gemm_kernel<<<dim3(16, 64), 256, 0, stream>>>(x, Wq, bq, qt, M, 1024, D_, 1);
    gemm_kernel<<<dim3(4,  64), 256, 0, stream>>>(x, Wk, bk, kt, M, 256,  D_, 1);
    gemm_kernel<<<dim3(4,  64), 256, 0, stream>>>(x, Wv, bv, vt, M, 256,  D_, 1);

    rope_cast_kernel<<<(B_ * H_ * S_ * 32) / 256, 256, 0, stream>>>(qt, qb, B_ * H_ * S_ * 32);
    rope_cast_kernel<<<(B_ * KH_ * S_ * 32) / 256, 256, 0, stream>>>(kt, kbq, B_ * KH_ * S_ * 32);
    transpose_v_kernel<<<B_ * KH_ * (S_ / 64), 256, 0, stream>>>(vt, vT);

    attn_mfma_kernel<<<B_ * H_ * (S_ / 64), 256, 0, stream>>>(qb, kbq, vT, ot);

    gemm_kernel<<<dim3(16, 64), 256, 0, stream>>>(ot, Wo, bo, out, M, 1024, D_, 0);
}

// Round 3
// 606.093 us; speedup vs baseline: 2.2628x; 1.0078x over previous
//
#include <hip/hip_runtime.h>
#include <math.h>

#define B_   2
#define S_   2048
#define D_   1024
#define H_   16
#define KH_  4
#define DK_  64

using bf16x8 = __attribute__((ext_vector_type(8))) short;
using f32x4  = __attribute__((ext_vector_type(4))) float;
using u32x4  = __attribute__((ext_vector_type(4))) unsigned int;

__device__ inline unsigned short f2bf(float f) {
    unsigned u = __float_as_uint(f);
    u += 0x7FFFu + ((u >> 16) & 1u);          // RNE
    return (unsigned short)(u >> 16);
}

// ---------------------------------------------------------------------------
// cast fp32 -> bf16, 8 elems/thread
// ---------------------------------------------------------------------------
__global__ __launch_bounds__(256) void cast_bf16_kernel(
    const float* __restrict__ in, unsigned short* __restrict__ out, int n8)
{
    const int i = blockIdx.x * 256 + threadIdx.x;
    if (i >= n8) return;
    f32x4 a = *(const f32x4*)(in + (long)i * 8);
    f32x4 b = *(const f32x4*)(in + (long)i * 8 + 4);
    bf16x8 o;
    o[0] = (short)f2bf(a[0]); o[1] = (short)f2bf(a[1]);
    o[2] = (short)f2bf(a[2]); o[3] = (short)f2bf(a[3]);
    o[4] = (short)f2bf(b[0]); o[5] = (short)f2bf(b[1]);
    o[6] = (short)f2bf(b[2]); o[7] = (short)f2bf(b[3]);
    *(bf16x8*)(out + (long)i * 8) = o;
}

// ---------------------------------------------------------------------------
// transpose + cast: in fp32 (R,C) -> out bf16 (C,R). 64x64 tiles.
// ---------------------------------------------------------------------------
__global__ __launch_bounds__(256) void transpose_cast_kernel(
    const float* __restrict__ in, unsigned short* __restrict__ out, int R, int C)
{
    __shared__ float T[64][65];
    const int bx = blockIdx.x;
    const int nr = R >> 6;
    const int r0 = (bx % nr) * 64;
    const int c0 = (bx / nr) * 64;
    const int t  = threadIdx.x;

    {   // load 64 r-rows x 64 c
        const int r  = t >> 2;
        const int cq = (t & 3) * 16;
        const float* src = in + (long)(r0 + r) * C + c0 + cq;
        #pragma unroll
        for (int i = 0; i < 4; ++i) {
            f32x4 v = *(const f32x4*)(src + i * 4);
            T[r][cq + i * 4 + 0] = v[0];
            T[r][cq + i * 4 + 1] = v[1];
            T[r][cq + i * 4 + 2] = v[2];
            T[r][cq + i * 4 + 3] = v[3];
        }
    }
    __syncthreads();
    {   // write 64 c-rows x 64 r
        const int c  = t >> 2;
        const int rq = (t & 3) * 16;
        bf16x8 p0, p1;
        #pragma unroll
        for (int i = 0; i < 8; ++i) {
            p0[i] = (short)f2bf(T[rq + i][c]);
            p1[i] = (short)f2bf(T[rq + 8 + i][c]);
        }
        unsigned short* dst = out + (long)(c0 + c) * R + r0 + rq;
        *(bf16x8*)dst       = p0;
        *(bf16x8*)(dst + 8) = p1;
    }
}

// ---------------------------------------------------------------------------
// bf16 MFMA GEMM, B-transposed inputs: C[M,N] = A[M,K] @ Bt[N,K]^T + bias
// 128x128 tile, BK=32, 256 thr = 4 waves in 2x2, each wave 64x64 (4x4 MFMA).
// mode 0: out fp32 [M,N]
// mode 1: RoPE + bf16 scatter to (B, N/64, S, 64)   (Q and K projections)
// mode 3: bf16 scatter to V^T (B, N/64, 64, S)      (V projection)
// ---------------------------------------------------------------------------
__global__ __launch_bounds__(256) void gemm_bt_kernel(
    const unsigned short* __restrict__ A,   // bf16 M x K
    const unsigned short* __restrict__ Bt,  // bf16 N x K
    const float* __restrict__ bias,
    float* __restrict__ outf,               // mode 0
    unsigned short* __restrict__ outb,      // mode 1/3
    int M, int N, int K, int mode)
{
    __shared__ unsigned short As[128][40];  // pad 8 -> 80B stride
    __shared__ unsigned short Bs[128][40];

    const int t  = threadIdx.x;
    const int m0 = blockIdx.y * 128;
    const int n0 = blockIdx.x * 128;

    const int w    = t >> 6;
    const int lane = t & 63;
    const int n    = lane & 15;
    const int quad = lane >> 4;
    const int wm   = (w >> 1) * 64;
    const int wn   = (w & 1) * 64;

    const int lr = t >> 2;          // 0..63 staging row
    const int lc = (t & 3) * 8;     // 0,8,16,24 bf16 col

    f32x4 acc[4][4];
    #pragma unroll
    for (int i = 0; i < 4; ++i)
        #pragma unroll
        for (int j = 0; j < 4; ++j) acc[i][j] = 0.0f;

    for (int k0 = 0; k0 < K; k0 += 32) {
        u32x4 a0 = *(const u32x4*)&A [(long)(m0 + lr)      * K + k0 + lc];
        u32x4 a1 = *(const u32x4*)&A [(long)(m0 + 64 + lr) * K + k0 + lc];
        u32x4 b0 = *(const u32x4*)&Bt[(long)(n0 + lr)      * K + k0 + lc];
        u32x4 b1 = *(const u32x4*)&Bt[(long)(n0 + 64 + lr) * K + k0 + lc];
        __syncthreads();
        *(u32x4*)&As[lr][lc]      = a0;
        *(u32x4*)&As[lr + 64][lc] = a1;
        *(u32x4*)&Bs[lr][lc]      = b0;
        *(u32x4*)&Bs[lr + 64][lc] = b1;
        __syncthreads();

        bf16x8 af[4], bf[4];
        #pragma unroll
        for (int i = 0; i < 4; ++i) {
            af[i] = *(const bf16x8*)&As[wm + i * 16 + n][quad * 8];
            bf[i] = *(const bf16x8*)&Bs[wn + i * 16 + n][quad * 8];
        }
        #pragma unroll
        for (int mi = 0; mi < 4; ++mi)
            #pragma unroll
            for (int ni = 0; ni < 4; ++ni)
                acc[mi][ni] = __builtin_amdgcn_mfma_f32_16x16x32_bf16(
                    af[mi], bf[ni], acc[mi][ni], 0, 0, 0);
    }

    // ---- epilogue ----
    const int NH = N >> 6;                 // heads in output
    const int hh = (n0 + wn) >> 6;         // head (modes 1/3), wave-uniform

    if (mode == 0) {
        #pragma unroll
        for (int mi = 0; mi < 4; ++mi) {
            #pragma unroll
            for (int r = 0; r < 4; ++r) {
                const int gm = m0 + wm + mi * 16 + quad * 4 + r;
                #pragma unroll
                for (int ni = 0; ni < 4; ++ni) {
                    const int gn = n0 + wn + ni * 16 + n;
                    outf[(long)gm * N + gn] = acc[mi][ni][r] + bias[gn];
                }
            }
        }
    } else if (mode == 1) {                // RoPE + scatter (B,NH,S,64) bf16
        #pragma unroll
        for (int mi = 0; mi < 4; ++mi) {
            #pragma unroll
            for (int r = 0; r < 4; ++r) {
                const int gm = m0 + wm + mi * 16 + quad * 4 + r;
                const int bb = gm >> 11;
                const int s  = gm & (S_ - 1);
                unsigned short* orow =
                    outb + ((long)(bb * NH + hh) * S_ + s) * DK_;
                #pragma unroll
                for (int ni = 0; ni < 2; ++ni) {
                    const int d    = ni * 16 + n;          // 0..31
                    const int col  = n0 + wn + ni * 16 + n;
                    const float x1 = acc[mi][ni][r]     + bias[col];
                    const float x2 = acc[mi][ni + 2][r] + bias[col + 32];
                    const float theta = expf(-(float)d * (9.210340371976184f / 32.0f));
                    const float f = (float)s * theta;
                    const float c = cosf(f), sn = sinf(f);
                    orow[d]      = f2bf(x1 * c - x2 * sn);
                    orow[d + 32] = f2bf(x2 * c + x1 * sn);
                }
            }
        }
    } else {                               // mode 3: V^T (B,NH,64,S) bf16
        #pragma unroll
        for (int mi = 0; mi < 4; ++mi) {
            #pragma unroll
            for (int r = 0; r < 4; ++r) {
                const int gm = m0 + wm + mi * 16 + quad * 4 + r;
                const int bb = gm >> 11;
                const int s  = gm & (S_ - 1);
                #pragma unroll
                for (int ni = 0; ni < 4; ++ni) {
                    const int d   = ni * 16 + n;
                    const int col = n0 + wn + ni * 16 + n;
                    const float v = acc[mi][ni][r] + bias[col];
                    outb[((long)(bb * NH + hh) * DK_ + d) * S_ + s] = f2bf(v);
                }
            }
        }
    }
}

// ---------------------------------------------------------------------------
// bf16 MFMA causal flash attention (unchanged from round 2 except bf16 out).
// ---------------------------------------------------------------------------
__global__ __launch_bounds__(256) void attn_mfma_kernel(
    const unsigned short* __restrict__ qb,   // (B,H,S,DK) bf16, roped
    const unsigned short* __restrict__ kbf,  // (B,KH,S,DK) bf16, roped
    const unsigned short* __restrict__ vT,   // (B,KH,DK,S) bf16
    unsigned short* __restrict__ ot)         // (B,S,H*DK) bf16
{
    __shared__ unsigned short Ks[64][72];
    __shared__ unsigned short Vs[64][72];
    __shared__ unsigned short Ps[4][16][72];

    const int tid = threadIdx.x;
    const int bx  = blockIdx.x;
    const int bh  = bx >> 5;
    const int b   = bh >> 4, h = bh & 15;
    const int kh  = h >> 2;
    const int rr  = bx & 31;
    const int qtile = (rr & 1) ? 31 - (rr >> 1) : (rr >> 1);
    const int q0  = qtile * 64;

    const int wv   = tid >> 6;
    const int lane = tid & 63;
    const int n    = lane & 15;
    const int quad = lane >> 4;

    const unsigned short* qp = qb + ((long)(b * H_ + h) * S_ + q0 + wv * 16 + n) * DK_;
    const bf16x8 qa0 = *(const bf16x8*)(qp + quad * 8);
    const bf16x8 qa1 = *(const bf16x8*)(qp + 32 + quad * 8);

    f32x4 O[4];
    #pragma unroll
    for (int dt = 0; dt < 4; ++dt) O[dt] = 0.0f;
    float mrun[4] = {-INFINITY, -INFINITY, -INFINITY, -INFINITY};
    float lrun[4] = {0.f, 0.f, 0.f, 0.f};

    const unsigned short* kbase = kbf + (long)(b * KH_ + kh) * S_ * DK_;
    const unsigned short* vbase = vT  + (long)(b * KH_ + kh) * DK_ * S_;

    const int ntiles = qtile + 1;
    const int rowg0  = q0 + wv * 16 + quad * 4;

    for (int t = 0; t < ntiles; ++t) {
        const int kb = t * 64;
        __syncthreads();
        #pragma unroll
        for (int i = 0; i < 2; ++i) {
            const int flat = tid + i * 256;
            const int row = flat >> 3, c8 = (flat & 7) * 8;
            *(u32x4*)&Ks[row][c8] = *(const u32x4*)(kbase + (long)(kb + row) * DK_ + c8);
            *(u32x4*)&Vs[row][c8] = *(const u32x4*)(vbase + (long)row * S_ + kb + c8);
        }
        __syncthreads();

        f32x4 sc[4];
        #pragma unroll
        for (int ct = 0; ct < 4; ++ct) {
            const bf16x8 b0 = *(const bf16x8*)&Ks[ct * 16 + n][quad * 8];
            const bf16x8 b1 = *(const bf16x8*)&Ks[ct * 16 + n][32 + quad * 8];
            f32x4 c = 0.0f;
            c = __builtin_amdgcn_mfma_f32_16x16x32_bf16(qa0, b0, c, 0, 0, 0);
            c = __builtin_amdgcn_mfma_f32_16x16x32_bf16(qa1, b1, c, 0, 0, 0);
            sc[ct] = c;
        }

        float cr[4];
        #pragma unroll
        for (int r = 0; r < 4; ++r) {
            float mx = -INFINITY;
            #pragma unroll
            for (int ct = 0; ct < 4; ++ct) {
                const int col = kb + ct * 16 + n;
                float s = sc[ct][r] * 0.125f;
                s = (col <= rowg0 + r) ? s : -INFINITY;
                sc[ct][r] = s;
                mx = fmaxf(mx, s);
            }
            mx = fmaxf(mx, __shfl_xor(mx, 1));
            mx = fmaxf(mx, __shfl_xor(mx, 2));
            mx = fmaxf(mx, __shfl_xor(mx, 4));
            mx = fmaxf(mx, __shfl_xor(mx, 8));
            const float mn = fmaxf(mrun[r], mx);
            const float c_ = expf(mrun[r] - mn);
            float rs = 0.f;
            #pragma unroll
            for (int ct = 0; ct < 4; ++ct) {
                const float p = expf(sc[ct][r] - mn);
                sc[ct][r] = p;
                rs += p;
            }
            rs += __shfl_xor(rs, 1);
            rs += __shfl_xor(rs, 2);
            rs += __shfl_xor(rs, 4);
            rs += __shfl_xor(rs, 8);
            lrun[r] = lrun[r] * c_ + rs;
            mrun[r] = mn;
            cr[r] = c_;
        }
        #pragma unroll
        for (int dt = 0; dt < 4; ++dt)
            #pragma unroll
            for (int r = 0; r < 4; ++r) O[dt][r] *= cr[r];

        #pragma unroll
        for (int ct = 0; ct < 4; ++ct)
            #pragma unroll
            for (int r = 0; r < 4; ++r)
                Ps[wv][quad * 4 + r][ct * 16 + n] = f2bf(sc[ct][r]);
        const bf16x8 pa0 = *(const bf16x8*)&Ps[wv][n][quad * 8];
        const bf16x8 pa1 = *(const bf16x8*)&Ps[wv][n][32 + quad * 8];

        #pragma unroll
        for (int dt = 0; dt < 4; ++dt) {
            const bf16x8 v0 = *(const bf16x8*)&Vs[dt * 16 + n][quad * 8];
            const bf16x8 v1 = *(const bf16x8*)&Vs[dt * 16 + n][32 + quad * 8];
            O[dt] = __builtin_amdgcn_mfma_f32_16x16x32_bf16(pa0, v0, O[dt], 0, 0, 0);
            O[dt] = __builtin_amdgcn_mfma_f32_16x16x32_bf16(pa1, v1, O[dt], 0, 0, 0);
        }
    }

    #pragma unroll
    for (int r = 0; r < 4; ++r) {
        const float inv = 1.0f / lrun[r];
        unsigned short* op = ot + ((long)(b * S_ + rowg0 + r) * H_ + h) * DK_;
        #pragma unroll
        for (int dt = 0; dt < 4; ++dt)
            op[dt * 16 + n] = f2bf(O[dt][r] * inv);
    }
}

// ---------------------------------------------------------------------------
extern "C" void kernel_launch(void* const* d_in, const int* in_sizes, int n_in,
                              void* d_out, int out_size, void* d_ws, size_t ws_size,
                              hipStream_t stream)
{
    const float* x  = (const float*)d_in[0];
    const float* Wq = (const float*)d_in[2];
    const float* bq = (const float*)d_in[3];
    const float* Wk = (const float*)d_in[4];
    const float* bk = (const float*)d_in[5];
    const float* Wv = (const float*)d_in[6];
    const float* bv = (const float*)d_in[7];
    const float* Wo = (const float*)d_in[8];
    const float* bo = (const float*)d_in[9];
    float* out = (float*)d_out;

    // Workspace (bf16 elements unless noted):
    unsigned short* ws  = (unsigned short*)d_ws;
    unsigned short* xb  = ws;                 // 4194304  x bf16
    unsigned short* qb  = xb  + 4194304;      // 4194304  roped Q (B,H,S,DK)
    unsigned short* kb  = qb  + 4194304;      // 1048576  roped K (B,KH,S,DK)
    unsigned short* vT  = kb  + 1048576;      // 1048576  V^T (B,KH,DK,S)
    unsigned short* ob  = vT  + 1048576;      // 4194304  attn out (B,S,H*DK)
    unsigned short* WqT = ob  + 4194304;      // 1048576
    unsigned short* WkT = WqT + 1048576;      //  262144
    unsigned short* WvT = WkT + 262144;       //  262144
    unsigned short* WoT = WvT + 262144;       // 1048576  (total ~34.2 MB)

    const int M = B_ * S_;                    // 4096

    cast_bf16_kernel<<<(M * D_ / 8) / 256, 256, 0, stream>>>(x, xb, M * D_ / 8);
    transpose_cast_kernel<<<(D_ / 64) * (1024 / 64), 256, 0, stream>>>(Wq, WqT, D_, 1024);
    transpose_cast_kernel<<<(D_ / 64) * (256 / 64),  256, 0, stream>>>(Wk, WkT, D_, 256);
    transpose_cast_kernel<<<(D_ / 64) * (256 / 64),  256, 0, stream>>>(Wv, WvT, D_, 256);
    transpose_cast_kernel<<<(1024 / 64) * (D_ / 64), 256, 0, stream>>>(Wo, WoT, 1024, D_);

    // Projections (fused rope / V-transpose epilogues)
    gemm_bt_kernel<<<dim3(8, 32), 256, 0, stream>>>(xb, WqT, bq, nullptr, qb, M, 1024, D_, 1);
    gemm_bt_kernel<<<dim3(2, 32), 256, 0, stream>>>(xb, WkT, bk, nullptr, kb, M, 256,  D_, 1);
    gemm_bt_kernel<<<dim3(2, 32), 256, 0, stream>>>(xb, WvT, bv, nullptr, vT, M, 256,  D_, 3);

    attn_mfma_kernel<<<B_ * H_ * (S_ / 64), 256, 0, stream>>>(qb, kb, vT, ob);

    gemm_bt_kernel<<<dim3(8, 32), 256, 0, stream>>>(ob, WoT, bo, out, nullptr, M, 1024, D_, 0);
}

// Round 4
// 422.427 us; speedup vs baseline: 3.2466x; 1.4348x over previous
//
#include <hip/hip_runtime.h>
#include <math.h>

#define B_   2
#define S_   2048
#define D_   1024
#define H_   16
#define KH_  4
#define DK_  64

using bf16x8 = __attribute__((ext_vector_type(8))) short;
using f32x4  = __attribute__((ext_vector_type(4))) float;
using u32x4  = __attribute__((ext_vector_type(4))) unsigned int;

__device__ inline unsigned short f2bf(float f) {
    unsigned u = __float_as_uint(f);
    u += 0x7FFFu + ((u >> 16) & 1u);          // RNE
    return (unsigned short)(u >> 16);
}

// ---------------------------------------------------------------------------
// cast fp32 -> bf16, 8 elems/thread
// ---------------------------------------------------------------------------
__global__ __launch_bounds__(256) void cast_bf16_kernel(
    const float* __restrict__ in, unsigned short* __restrict__ out, int n8)
{
    const int i = blockIdx.x * 256 + threadIdx.x;
    if (i >= n8) return;
    f32x4 a = *(const f32x4*)(in + (long)i * 8);
    f32x4 b = *(const f32x4*)(in + (long)i * 8 + 4);
    bf16x8 o;
    o[0] = (short)f2bf(a[0]); o[1] = (short)f2bf(a[1]);
    o[2] = (short)f2bf(a[2]); o[3] = (short)f2bf(a[3]);
    o[4] = (short)f2bf(b[0]); o[5] = (short)f2bf(b[1]);
    o[6] = (short)f2bf(b[2]); o[7] = (short)f2bf(b[3]);
    *(bf16x8*)(out + (long)i * 8) = o;
}

// ---------------------------------------------------------------------------
// transpose + cast: in fp32 (R,C) -> out bf16 (C,R). 64x64 tiles.
// ---------------------------------------------------------------------------
__global__ __launch_bounds__(256) void transpose_cast_kernel(
    const float* __restrict__ in, unsigned short* __restrict__ out, int R, int C)
{
    __shared__ float T[64][65];
    const int bx = blockIdx.x;
    const int nr = R >> 6;
    const int r0 = (bx % nr) * 64;
    const int c0 = (bx / nr) * 64;
    const int t  = threadIdx.x;

    {
        const int r  = t >> 2;
        const int cq = (t & 3) * 16;
        const float* src = in + (long)(r0 + r) * C + c0 + cq;
        #pragma unroll
        for (int i = 0; i < 4; ++i) {
            f32x4 v = *(const f32x4*)(src + i * 4);
            T[r][cq + i * 4 + 0] = v[0];
            T[r][cq + i * 4 + 1] = v[1];
            T[r][cq + i * 4 + 2] = v[2];
            T[r][cq + i * 4 + 3] = v[3];
        }
    }
    __syncthreads();
    {
        const int c  = t >> 2;
        const int rq = (t & 3) * 16;
        bf16x8 p0, p1;
        #pragma unroll
        for (int i = 0; i < 8; ++i) {
            p0[i] = (short)f2bf(T[rq + i][c]);
            p1[i] = (short)f2bf(T[rq + 8 + i][c]);
        }
        unsigned short* dst = out + (long)(c0 + c) * R + r0 + rq;
        *(bf16x8*)dst       = p0;
        *(bf16x8*)(dst + 8) = p1;
    }
}

// ---------------------------------------------------------------------------
// bf16 MFMA GEMM, B-transposed: C[M,N] = A[M,K] @ Bt[N,K]^T + bias.
// 128xBN tile, BK=32, 256 thr = 4 waves (2x2), register-prefetch pipeline.
// MODE 0 (BN=64):  fp32 out [M,N]
// MODE 1 (BN=128): fused QKV scatter: cols 0-1023 Q(rope->outq),
//                  1024-1279 K(rope->outk), 1280-1535 V(->outv V^T)
// ---------------------------------------------------------------------------
template<int BN, int MODE>
__global__ __launch_bounds__(256) void gemm_bt(
    const unsigned short* __restrict__ A,
    const unsigned short* __restrict__ Bt,
    const float* __restrict__ bias0,    // MODE0: bias; MODE1: bq
    const float* __restrict__ bias1,    // bk
    const float* __restrict__ bias2,    // bv
    float* __restrict__ outf,
    unsigned short* __restrict__ outq,
    unsigned short* __restrict__ outk,
    unsigned short* __restrict__ outv,
    int M, int N, int K)
{
    constexpr int NI = BN / 32;               // acc cols per wave
    __shared__ unsigned short As[128][40];    // pad 8 keeps 16B align
    __shared__ unsigned short Bs[BN][40];

    const int t  = threadIdx.x;
    const int m0 = blockIdx.y * 128;
    const int n0 = blockIdx.x * BN;

    const int w    = t >> 6;
    const int lane = t & 63;
    const int n    = lane & 15;
    const int quad = lane >> 4;
    const int wm   = (w >> 1) * 64;
    const int wn   = (w & 1) * (BN / 2);

    const int lr = t >> 2;
    const int lc = (t & 3) * 8;

    f32x4 acc[4][NI];
    #pragma unroll
    for (int i = 0; i < 4; ++i)
        #pragma unroll
        for (int j = 0; j < NI; ++j) acc[i][j] = 0.0f;

    // prefetch regs (tile 0)
    u32x4 ar0 = *(const u32x4*)&A [(long)(m0 + lr)      * K + lc];
    u32x4 ar1 = *(const u32x4*)&A [(long)(m0 + 64 + lr) * K + lc];
    u32x4 br0 = *(const u32x4*)&Bt[(long)(n0 + lr)      * K + lc];
    u32x4 br1;
    if constexpr (BN == 128)
        br1 = *(const u32x4*)&Bt[(long)(n0 + 64 + lr) * K + lc];

    for (int k0 = 0; k0 < K; k0 += 32) {
        __syncthreads();                       // prev readers done
        *(u32x4*)&As[lr][lc]      = ar0;
        *(u32x4*)&As[lr + 64][lc] = ar1;
        *(u32x4*)&Bs[lr][lc]      = br0;
        if constexpr (BN == 128) *(u32x4*)&Bs[lr + 64][lc] = br1;
        __syncthreads();                       // writes visible

        if (k0 + 32 < K) {                     // issue next loads early:
            ar0 = *(const u32x4*)&A [(long)(m0 + lr)      * K + k0 + 32 + lc];
            ar1 = *(const u32x4*)&A [(long)(m0 + 64 + lr) * K + k0 + 32 + lc];
            br0 = *(const u32x4*)&Bt[(long)(n0 + lr)      * K + k0 + 32 + lc];
            if constexpr (BN == 128)
                br1 = *(const u32x4*)&Bt[(long)(n0 + 64 + lr) * K + k0 + 32 + lc];
        }

        bf16x8 af[4], bfr[NI];
        #pragma unroll
        for (int i = 0; i < 4; ++i)
            af[i] = *(const bf16x8*)&As[wm + i * 16 + n][quad * 8];
        #pragma unroll
        for (int j = 0; j < NI; ++j)
            bfr[j] = *(const bf16x8*)&Bs[wn + j * 16 + n][quad * 8];
        #pragma unroll
        for (int mi = 0; mi < 4; ++mi)
            #pragma unroll
            for (int ni = 0; ni < NI; ++ni)
                acc[mi][ni] = __builtin_amdgcn_mfma_f32_16x16x32_bf16(
                    af[mi], bfr[ni], acc[mi][ni], 0, 0, 0);
    }

    // ---- epilogue ----
    if constexpr (MODE == 0) {
        #pragma unroll
        for (int mi = 0; mi < 4; ++mi) {
            #pragma unroll
            for (int r = 0; r < 4; ++r) {
                const int gm = m0 + wm + mi * 16 + quad * 4 + r;
                #pragma unroll
                for (int ni = 0; ni < NI; ++ni) {
                    const int gn = n0 + wn + ni * 16 + n;
                    outf[(long)gm * N + gn] = acc[mi][ni][r] + bias0[gn];
                }
            }
        }
    } else {
        const int colbase = n0 + wn;          // 64-aligned, wave-uniform
        const int seg = colbase >> 6;         // 0..23
        // rope thetas for this lane's two d values
        const float th0 = exp2f(-(float)(n)      * (13.287712379549449f / 32.0f));
        const float th1 = exp2f(-(float)(16 + n) * (13.287712379549449f / 32.0f));
        #pragma unroll
        for (int mi = 0; mi < 4; ++mi) {
            #pragma unroll
            for (int r = 0; r < 4; ++r) {
                const int gm = m0 + wm + mi * 16 + quad * 4 + r;
                const int bb = gm >> 11;
                const int s  = gm & (S_ - 1);
                if (seg < 16) {               // Q: rope
                    unsigned short* orow =
                        outq + ((long)(bb * H_ + seg) * S_ + s) * DK_;
                    #pragma unroll
                    for (int ni = 0; ni < 2; ++ni) {
                        const int d   = ni * 16 + n;
                        const int col = colbase + d;
                        const float x1 = acc[mi][ni][r]     + bias0[col];
                        const float x2 = acc[mi][ni + 2][r] + bias0[col + 32];
                        const float f = (float)s * (ni ? th1 : th0);
                        const float c = cosf(f), sn = sinf(f);
                        orow[d]      = f2bf(x1 * c - x2 * sn);
                        orow[d + 32] = f2bf(x2 * c + x1 * sn);
                    }
                } else if (seg < 20) {        // K: rope
                    unsigned short* orow =
                        outk + ((long)(bb * KH_ + (seg - 16)) * S_ + s) * DK_;
                    #pragma unroll
                    for (int ni = 0; ni < 2; ++ni) {
                        const int d   = ni * 16 + n;
                        const int col = colbase + d;
                        const float x1 = acc[mi][ni][r]     + bias1[col - 1024];
                        const float x2 = acc[mi][ni + 2][r] + bias1[col - 1024 + 32];
                        const float f = (float)s * (ni ? th1 : th0);
                        const float c = cosf(f), sn = sinf(f);
                        orow[d]      = f2bf(x1 * c - x2 * sn);
                        orow[d + 32] = f2bf(x2 * c + x1 * sn);
                    }
                } else {                      // V -> V^T
                    const int hv = seg - 20;
                    #pragma unroll
                    for (int ni = 0; ni < 4; ++ni) {
                        const int d   = ni * 16 + n;
                        const int col = colbase + d;
                        const float v = acc[mi][ni][r] + bias2[col - 1280];
                        outv[((long)(bb * KH_ + hv) * DK_ + d) * S_ + s] = f2bf(v);
                    }
                }
            }
        }
    }
}

// ---------------------------------------------------------------------------
// bf16 MFMA causal flash attention, v2.
// 256 thr = 4 waves; wave = 32 queries (2 m-frags); block = 128-query tile.
// Double-buffered 64-key K/V LDS tiles, register prefetch, ONE barrier/iter.
// log2-domain online softmax (exp2). Mask only on diagonal tiles.
// ---------------------------------------------------------------------------
__global__ __launch_bounds__(256) void attn_mfma_kernel(
    const unsigned short* __restrict__ qb,   // (B,H,S,DK) bf16, roped
    const unsigned short* __restrict__ kbf,  // (B,KH,S,DK) bf16, roped
    const unsigned short* __restrict__ vT,   // (B,KH,DK,S) bf16
    unsigned short* __restrict__ ot)         // (B,S,H*DK) bf16
{
    __shared__ unsigned short Ks[2][64][72];
    __shared__ unsigned short Vs[2][64][72];
    __shared__ unsigned short Ps[4][32][72];

    const int tid = threadIdx.x;
    const int bx  = blockIdx.x;
    const int bh  = bx >> 4;
    const int b   = bh >> 4, h = bh & 15;
    const int kh  = h >> 2;
    const int jj  = bx & 15;
    const int q0  = jj * 128;

    const int wv   = tid >> 6;
    const int lane = tid & 63;
    const int n    = lane & 15;
    const int quad = lane >> 4;

    // Q A-frags: 2 m-frags of 16 queries each
    const unsigned short* qp =
        qb + ((long)(b * H_ + h) * S_ + q0 + wv * 32 + n) * DK_;
    bf16x8 qa[2][2];
    qa[0][0] = *(const bf16x8*)(qp + quad * 8);
    qa[0][1] = *(const bf16x8*)(qp + 32 + quad * 8);
    qa[1][0] = *(const bf16x8*)(qp + 16 * DK_ + quad * 8);
    qa[1][1] = *(const bf16x8*)(qp + 16 * DK_ + 32 + quad * 8);

    f32x4 O[2][4];
    #pragma unroll
    for (int i = 0; i < 2; ++i)
        #pragma unroll
        for (int dt = 0; dt < 4; ++dt) O[i][dt] = 0.0f;
    float mrun[2][4], lrun[2][4];
    #pragma unroll
    for (int i = 0; i < 2; ++i)
        #pragma unroll
        for (int r = 0; r < 4; ++r) { mrun[i][r] = -INFINITY; lrun[i][r] = 0.f; }

    const unsigned short* kbase = kbf + (long)(b * KH_ + kh) * S_ * DK_;
    const unsigned short* vbase = vT  + (long)(b * KH_ + kh) * DK_ * S_;

    const int ntiles = 2 * jj + 2;
    const int srow = tid >> 3;          // 0..31
    const int sc8  = (tid & 7) * 8;

    // stage tile 0 into buf 0
    u32x4 kr0 = *(const u32x4*)(kbase + (long)srow * DK_ + sc8);
    u32x4 kr1 = *(const u32x4*)(kbase + (long)(32 + srow) * DK_ + sc8);
    u32x4 vr0 = *(const u32x4*)(vbase + (long)srow * S_ + sc8);
    u32x4 vr1 = *(const u32x4*)(vbase + (long)(32 + srow) * S_ + sc8);
    *(u32x4*)&Ks[0][srow][sc8]      = kr0;
    *(u32x4*)&Ks[0][32 + srow][sc8] = kr1;
    *(u32x4*)&Vs[0][srow][sc8]      = vr0;
    *(u32x4*)&Vs[0][32 + srow][sc8] = vr1;

    const float sfac = 0.125f * 1.44269504f;   // 1/sqrt(64) * log2(e)

    for (int u = 0; u < ntiles; ++u) {
        const int cur = u & 1;
        const int kb  = u * 64;
        __syncthreads();   // buf[cur] writes visible; prev readers of buf[cur^1] done

        if (u + 1 < ntiles) {                  // prefetch next tile -> regs
            const int kbn = kb + 64;
            kr0 = *(const u32x4*)(kbase + (long)(kbn + srow) * DK_ + sc8);
            kr1 = *(const u32x4*)(kbase + (long)(kbn + 32 + srow) * DK_ + sc8);
            vr0 = *(const u32x4*)(vbase + (long)srow * S_ + kbn + sc8);
            vr1 = *(const u32x4*)(vbase + (long)(32 + srow) * S_ + kbn + sc8);
        }

        // ---- QK^T: 32 q x 64 k ----
        bf16x8 kf0[4], kf1[4];
        #pragma unroll
        for (int ct = 0; ct < 4; ++ct) {
            kf0[ct] = *(const bf16x8*)&Ks[cur][ct * 16 + n][quad * 8];
            kf1[ct] = *(const bf16x8*)&Ks[cur][ct * 16 + n][32 + quad * 8];
        }
        f32x4 sc[2][4];
        #pragma unroll
        for (int i = 0; i < 2; ++i)
            #pragma unroll
            for (int ct = 0; ct < 4; ++ct) {
                f32x4 c = 0.0f;
                c = __builtin_amdgcn_mfma_f32_16x16x32_bf16(qa[i][0], kf0[ct], c, 0, 0, 0);
                c = __builtin_amdgcn_mfma_f32_16x16x32_bf16(qa[i][1], kf1[ct], c, 0, 0, 0);
                sc[i][ct] = c;
            }

        // ---- online softmax (log2 domain) ----
        const bool domask = (u >= 2 * jj);     // only diagonal tiles
        float cr[2][4];
        #pragma unroll
        for (int i = 0; i < 2; ++i) {
            const int rg = q0 + wv * 32 + i * 16 + quad * 4;
            #pragma unroll
            for (int r = 0; r < 4; ++r) {
                float mx = -INFINITY;
                #pragma unroll
                for (int ct = 0; ct < 4; ++ct) {
                    float s = sc[i][ct][r] * sfac;
                    if (domask) {
                        const int col = kb + ct * 16 + n;
                        s = (col <= rg + r) ? s : -INFINITY;
                    }
                    sc[i][ct][r] = s;
                    mx = fmaxf(mx, s);
                }
                mx = fmaxf(mx, __shfl_xor(mx, 1));
                mx = fmaxf(mx, __shfl_xor(mx, 2));
                mx = fmaxf(mx, __shfl_xor(mx, 4));
                mx = fmaxf(mx, __shfl_xor(mx, 8));
                const float mn = fmaxf(mrun[i][r], mx);
                const float c_ = exp2f(mrun[i][r] - mn);
                float rs = 0.f;
                #pragma unroll
                for (int ct = 0; ct < 4; ++ct) {
                    const float p = exp2f(sc[i][ct][r] - mn);
                    sc[i][ct][r] = p;
                    rs += p;
                }
                rs += __shfl_xor(rs, 1);
                rs += __shfl_xor(rs, 2);
                rs += __shfl_xor(rs, 4);
                rs += __shfl_xor(rs, 8);
                lrun[i][r] = lrun[i][r] * c_ + rs;
                mrun[i][r] = mn;
                cr[i][r] = c_;
            }
        }
        #pragma unroll
        for (int i = 0; i < 2; ++i)
            #pragma unroll
            for (int dt = 0; dt < 4; ++dt)
                #pragma unroll
                for (int r = 0; r < 4; ++r) O[i][dt][r] *= cr[i][r];

        // ---- P -> per-wave LDS -> A-frags ----
        #pragma unroll
        for (int i = 0; i < 2; ++i)
            #pragma unroll
            for (int ct = 0; ct < 4; ++ct)
                #pragma unroll
                for (int r = 0; r < 4; ++r)
                    Ps[wv][i * 16 + quad * 4 + r][ct * 16 + n] = f2bf(sc[i][ct][r]);
        bf16x8 pa[2][2];
        #pragma unroll
        for (int i = 0; i < 2; ++i) {
            pa[i][0] = *(const bf16x8*)&Ps[wv][i * 16 + n][quad * 8];
            pa[i][1] = *(const bf16x8*)&Ps[wv][i * 16 + n][32 + quad * 8];
        }

        // ---- PV ----
        #pragma unroll
        for (int dt = 0; dt < 4; ++dt) {
            const bf16x8 v0 = *(const bf16x8*)&Vs[cur][dt * 16 + n][quad * 8];
            const bf16x8 v1 = *(const bf16x8*)&Vs[cur][dt * 16 + n][32 + quad * 8];
            #pragma unroll
            for (int i = 0; i < 2; ++i) {
                O[i][dt] = __builtin_amdgcn_mfma_f32_16x16x32_bf16(pa[i][0], v0, O[i][dt], 0, 0, 0);
                O[i][dt] = __builtin_amdgcn_mfma_f32_16x16x32_bf16(pa[i][1], v1, O[i][dt], 0, 0, 0);
            }
        }

        // ---- write prefetched tile into other buffer (no barrier needed:
        //      next iter's top barrier orders it before its readers) ----
        if (u + 1 < ntiles) {
            const int nb = cur ^ 1;
            *(u32x4*)&Ks[nb][srow][sc8]      = kr0;
            *(u32x4*)&Ks[nb][32 + srow][sc8] = kr1;
            *(u32x4*)&Vs[nb][srow][sc8]      = vr0;
            *(u32x4*)&Vs[nb][32 + srow][sc8] = vr1;
        }
    }

    // ---- epilogue ----
    #pragma unroll
    for (int i = 0; i < 2; ++i) {
        const int rg = q0 + wv * 32 + i * 16 + quad * 4;
        #pragma unroll
        for (int r = 0; r < 4; ++r) {
            const float inv = 1.0f / lrun[i][r];
            unsigned short* op = ot + ((long)(b * S_ + rg + r) * H_ + h) * DK_;
            #pragma unroll
            for (int dt = 0; dt < 4; ++dt)
                op[dt * 16 + n] = f2bf(O[i][dt][r] * inv);
        }
    }
}

// ---------------------------------------------------------------------------
extern "C" void kernel_launch(void* const* d_in, const int* in_sizes, int n_in,
                              void* d_out, int out_size, void* d_ws, size_t ws_size,
                              hipStream_t stream)
{
    const float* x  = (const float*)d_in[0];
    const float* Wq = (const float*)d_in[2];
    const float* bq = (const float*)d_in[3];
    const float* Wk = (const float*)d_in[4];
    const float* bk = (const float*)d_in[5];
    const float* Wv = (const float*)d_in[6];
    const float* bv = (const float*)d_in[7];
    const float* Wo = (const float*)d_in[8];
    const float* bo = (const float*)d_in[9];
    float* out = (float*)d_out;

    // Workspace (bf16 elements): 34.6 MB total
    unsigned short* ws     = (unsigned short*)d_ws;
    unsigned short* xb     = ws;                  // 4194304
    unsigned short* qbuf   = xb + 4194304;        // 4194304  roped Q (B,H,S,DK)
    unsigned short* kbuf   = qbuf + 4194304;      // 1048576  roped K (B,KH,S,DK)
    unsigned short* vbuf   = kbuf + 1048576;      // 1048576  V^T (B,KH,DK,S)
    unsigned short* ob     = vbuf + 1048576;      // 4194304  attn out (B,S,H*DK)
    unsigned short* WqkvT  = ob + 4194304;        // 1572864  [1536 x 1024]
    unsigned short* WoT    = WqkvT + 1572864;     // 1048576

    const int M = B_ * S_;                        // 4096

    cast_bf16_kernel<<<(M * D_ / 8) / 256, 256, 0, stream>>>(x, xb, M * D_ / 8);
    transpose_cast_kernel<<<256, 256, 0, stream>>>(Wq, WqkvT,                1024, 1024);
    transpose_cast_kernel<<<64,  256, 0, stream>>>(Wk, WqkvT + 1024 * 1024, 1024, 256);
    transpose_cast_kernel<<<64,  256, 0, stream>>>(Wv, WqkvT + 1280 * 1024, 1024, 256);
    transpose_cast_kernel<<<256, 256, 0, stream>>>(Wo, WoT,                 1024, 1024);

    // Fused QKV projection + rope + V-transpose epilogues
    gemm_bt<128, 1><<<dim3(12, 32), 256, 0, stream>>>(
        xb, WqkvT, bq, bk, bv, nullptr, qbuf, kbuf, vbuf, M, 1536, D_);

    attn_mfma_kernel<<<B_ * H_ * (S_ / 128), 256, 0, stream>>>(qbuf, kbuf, vbuf, ob);

    // Output projection
    gemm_bt<64, 0><<<dim3(16, 32), 256, 0, stream>>>(
        ob, WoT, bo, nullptr, nullptr, out, nullptr, nullptr, nullptr, M, 1024, D_);
}

// Round 5
// 402.166 us; speedup vs baseline: 3.4102x; 1.0504x over previous
//
#include <hip/hip_runtime.h>
#include <math.h>

#define B_   2
#define S_   2048
#define D_   1024
#define H_   16
#define KH_  4
#define DK_  64

using bf16x8 = __attribute__((ext_vector_type(8))) short;
using f32x4  = __attribute__((ext_vector_type(4))) float;
using u32x4  = __attribute__((ext_vector_type(4))) unsigned int;

__device__ inline unsigned short f2bf(float f) {
    unsigned u = __float_as_uint(f);
    u += 0x7FFFu + ((u >> 16) & 1u);          // RNE
    return (unsigned short)(u >> 16);
}

// ---------------------------------------------------------------------------
// cast fp32 -> bf16, 8 elems/thread
// ---------------------------------------------------------------------------
__global__ __launch_bounds__(256) void cast_bf16_kernel(
    const float* __restrict__ in, unsigned short* __restrict__ out, int n8)
{
    const int i = blockIdx.x * 256 + threadIdx.x;
    if (i >= n8) return;
    f32x4 a = *(const f32x4*)(in + (long)i * 8);
    f32x4 b = *(const f32x4*)(in + (long)i * 8 + 4);
    bf16x8 o;
    o[0] = (short)f2bf(a[0]); o[1] = (short)f2bf(a[1]);
    o[2] = (short)f2bf(a[2]); o[3] = (short)f2bf(a[3]);
    o[4] = (short)f2bf(b[0]); o[5] = (short)f2bf(b[1]);
    o[6] = (short)f2bf(b[2]); o[7] = (short)f2bf(b[3]);
    *(bf16x8*)(out + (long)i * 8) = o;
}

// ---------------------------------------------------------------------------
// transpose + cast: in fp32 (R,C) -> out bf16 (C,R). 64x64 tiles.
// ---------------------------------------------------------------------------
__global__ __launch_bounds__(256) void transpose_cast_kernel(
    const float* __restrict__ in, unsigned short* __restrict__ out, int R, int C)
{
    __shared__ float T[64][65];
    const int bx = blockIdx.x;
    const int nr = R >> 6;
    const int r0 = (bx % nr) * 64;
    const int c0 = (bx / nr) * 64;
    const int t  = threadIdx.x;

    {
        const int r  = t >> 2;
        const int cq = (t & 3) * 16;
        const float* src = in + (long)(r0 + r) * C + c0 + cq;
        #pragma unroll
        for (int i = 0; i < 4; ++i) {
            f32x4 v = *(const f32x4*)(src + i * 4);
            T[r][cq + i * 4 + 0] = v[0];
            T[r][cq + i * 4 + 1] = v[1];
            T[r][cq + i * 4 + 2] = v[2];
            T[r][cq + i * 4 + 3] = v[3];
        }
    }
    __syncthreads();
    {
        const int c  = t >> 2;
        const int rq = (t & 3) * 16;
        bf16x8 p0, p1;
        #pragma unroll
        for (int i = 0; i < 8; ++i) {
            p0[i] = (short)f2bf(T[rq + i][c]);
            p1[i] = (short)f2bf(T[rq + 8 + i][c]);
        }
        unsigned short* dst = out + (long)(c0 + c) * R + r0 + rq;
        *(bf16x8*)dst       = p0;
        *(bf16x8*)(dst + 8) = p1;
    }
}

// ---------------------------------------------------------------------------
// bf16 MFMA GEMM, B-transposed: C[M,N] = A[M,K] @ Bt[N,K]^T + bias.
// 128xBN tile, BK=32, 256 thr = 4 waves (2x2), register-prefetch pipeline.
// Grid: blockIdx.x = M-tile (same-M blocks share A and land on one XCD via
// the g%8 dispatch heuristic), blockIdx.y = N-tile.
// MODE 0 (BN=64):  fp32 out [M,N] (already full-line coalesced)
// MODE 1 (BN=128): fused QKV epilogue, LDS-staged so ALL global stores are
//   full-line bf16x8 writes (round-4 scatter epilogue caused 47x write amp):
//   cols 0-1023 Q (rope -> outq), 1024-1279 K (rope -> outk),
//   1280-1535 V (-> outv V^T layout).
// ---------------------------------------------------------------------------
template<int BN, int MODE>
__global__ __launch_bounds__(256) void gemm_bt(
    const unsigned short* __restrict__ A,
    const unsigned short* __restrict__ Bt,
    const float* __restrict__ bias0,    // MODE0: bias; MODE1: bq
    const float* __restrict__ bias1,    // bk
    const float* __restrict__ bias2,    // bv
    float* __restrict__ outf,
    unsigned short* __restrict__ outq,
    unsigned short* __restrict__ outk,
    unsigned short* __restrict__ outv,
    int M, int N, int K)
{
    constexpr int NI  = BN / 32;              // acc cols per wave
    constexpr int RAW = (MODE == 1) ? (4 * 64 * 76) : (128 * 40 + BN * 40);
    __shared__ unsigned short raw[RAW];
    unsigned short (*As)[40] = (unsigned short(*)[40])raw;
    unsigned short (*Bs)[40] = (unsigned short(*)[40])(raw + 128 * 40);

    const int t  = threadIdx.x;
    const int m0 = blockIdx.x * 128;
    const int n0 = blockIdx.y * BN;

    const int w    = t >> 6;
    const int lane = t & 63;
    const int n    = lane & 15;
    const int quad = lane >> 4;
    const int wm   = (w >> 1) * 64;
    const int wn   = (w & 1) * (BN / 2);

    const int lr = t >> 2;
    const int lc = (t & 3) * 8;

    f32x4 acc[4][NI];
    #pragma unroll
    for (int i = 0; i < 4; ++i)
        #pragma unroll
        for (int j = 0; j < NI; ++j) acc[i][j] = 0.0f;

    // prefetch regs (tile 0)
    u32x4 ar0 = *(const u32x4*)&A [(long)(m0 + lr)      * K + lc];
    u32x4 ar1 = *(const u32x4*)&A [(long)(m0 + 64 + lr) * K + lc];
    u32x4 br0 = *(const u32x4*)&Bt[(long)(n0 + lr)      * K + lc];
    u32x4 br1;
    if constexpr (BN == 128)
        br1 = *(const u32x4*)&Bt[(long)(n0 + 64 + lr) * K + lc];

    for (int k0 = 0; k0 < K; k0 += 32) {
        __syncthreads();                       // prev readers done
        *(u32x4*)&As[lr][lc]      = ar0;
        *(u32x4*)&As[lr + 64][lc] = ar1;
        *(u32x4*)&Bs[lr][lc]      = br0;
        if constexpr (BN == 128) *(u32x4*)&Bs[lr + 64][lc] = br1;
        __syncthreads();                       // writes visible

        if (k0 + 32 < K) {                     // issue next loads early
            ar0 = *(const u32x4*)&A [(long)(m0 + lr)      * K + k0 + 32 + lc];
            ar1 = *(const u32x4*)&A [(long)(m0 + 64 + lr) * K + k0 + 32 + lc];
            br0 = *(const u32x4*)&Bt[(long)(n0 + lr)      * K + k0 + 32 + lc];
            if constexpr (BN == 128)
                br1 = *(const u32x4*)&Bt[(long)(n0 + 64 + lr) * K + k0 + 32 + lc];
        }

        bf16x8 af[4], bfr[NI];
        #pragma unroll
        for (int i = 0; i < 4; ++i)
            af[i] = *(const bf16x8*)&As[wm + i * 16 + n][quad * 8];
        #pragma unroll
        for (int j = 0; j < NI; ++j)
            bfr[j] = *(const bf16x8*)&Bs[wn + j * 16 + n][quad * 8];
        #pragma unroll
        for (int mi = 0; mi < 4; ++mi)
            #pragma unroll
            for (int ni = 0; ni < NI; ++ni)
                acc[mi][ni] = __builtin_amdgcn_mfma_f32_16x16x32_bf16(
                    af[mi], bfr[ni], acc[mi][ni], 0, 0, 0);
    }

    // ---- epilogue ----
    if constexpr (MODE == 0) {
        #pragma unroll
        for (int mi = 0; mi < 4; ++mi) {
            #pragma unroll
            for (int r = 0; r < 4; ++r) {
                const int gm = m0 + wm + mi * 16 + quad * 4 + r;
                #pragma unroll
                for (int ni = 0; ni < NI; ++ni) {
                    const int gn = n0 + wn + ni * 16 + n;
                    outf[(long)gm * N + gn] = acc[mi][ni][r] + bias0[gn];
                }
            }
        }
    } else {
        // LDS-staged epilogue: per-wave 64x64 tile in E[wv], then full-line
        // coalesced stores (8 lanes cover one contiguous 128B row).
        unsigned short (*E)[64][76] = (unsigned short(*)[64][76])raw;
        const int colbase = n0 + wn;          // 64-aligned, wave-uniform
        const int seg     = colbase >> 6;     // 0..23
        const int mbase   = m0 + wm;          // wave's 64 rows
        const int bb      = mbase >> 11;
        const int sbase   = mbase & (S_ - 1);

        __syncthreads();                      // all waves done with As/Bs

        if (seg < 20) {                       // Q or K: rope into E[rows=s][cols=d]
            const float th0 = exp2f(-(float)(n)      * (13.287712379549449f / 32.0f));
            const float th1 = exp2f(-(float)(16 + n) * (13.287712379549449f / 32.0f));
            const float* bias = (seg < 16) ? bias0 : bias1;
            const int    cb   = (seg < 16) ? colbase : colbase - 1024;
            #pragma unroll
            for (int mi = 0; mi < 4; ++mi) {
                #pragma unroll
                for (int r = 0; r < 4; ++r) {
                    const int row = mi * 16 + quad * 4 + r;
                    const int s   = sbase + row;
                    #pragma unroll
                    for (int ni = 0; ni < 2; ++ni) {
                        const int d = ni * 16 + n;
                        const float x1 = acc[mi][ni][r]     + bias[cb + d];
                        const float x2 = acc[mi][ni + 2][r] + bias[cb + d + 32];
                        const float f  = (float)s * (ni ? th1 : th0);
                        const float c = cosf(f), sn = sinf(f);
                        E[w][row][d]      = f2bf(x1 * c - x2 * sn);
                        E[w][row][d + 32] = f2bf(x2 * c + x1 * sn);
                    }
                }
            }
        } else {                              // V: transpose into E[d][s_local]
            #pragma unroll
            for (int mi = 0; mi < 4; ++mi) {
                #pragma unroll
                for (int r = 0; r < 4; ++r) {
                    const int row = mi * 16 + quad * 4 + r;
                    #pragma unroll
                    for (int ni = 0; ni < 4; ++ni) {
                        const int d = ni * 16 + n;
                        E[w][d][row] = f2bf(acc[mi][ni][r] + bias2[colbase - 1280 + d]);
                    }
                }
            }
        }
        __syncthreads();                      // E visible (block-wide, safe)

        const int fr = lane >> 3;             // 0..7
        const int c8 = (lane & 7) * 8;        // 0..56
        if (seg < 16) {                       // Q rows: contiguous 128B each
            unsigned short* base = outq + ((long)(bb * H_ + seg) * S_ + sbase) * DK_;
            #pragma unroll
            for (int it = 0; it < 8; ++it) {
                const int row = it * 8 + fr;
                *(bf16x8*)(base + row * DK_ + c8) = *(const bf16x8*)&E[w][row][c8];
            }
        } else if (seg < 20) {                // K rows
            unsigned short* base = outk + ((long)(bb * KH_ + (seg - 16)) * S_ + sbase) * DK_;
            #pragma unroll
            for (int it = 0; it < 8; ++it) {
                const int row = it * 8 + fr;
                *(bf16x8*)(base + row * DK_ + c8) = *(const bf16x8*)&E[w][row][c8];
            }
        } else {                              // V^T: per d, 128B contiguous s-span
            const int hv = seg - 20;
            unsigned short* base = outv + (long)(bb * KH_ + hv) * DK_ * S_ + sbase;
            #pragma unroll
            for (int it = 0; it < 8; ++it) {
                const int d = it * 8 + fr;
                *(bf16x8*)(base + (long)d * S_ + c8) = *(const bf16x8*)&E[w][d][c8];
            }
        }
    }
}

// ---------------------------------------------------------------------------
// bf16 MFMA causal flash attention (unchanged from round 4).
// 256 thr = 4 waves; wave = 32 queries; block = 128-query tile.
// Double-buffered 64-key K/V LDS tiles, register prefetch, ONE barrier/iter.
// ---------------------------------------------------------------------------
__global__ __launch_bounds__(256) void attn_mfma_kernel(
    const unsigned short* __restrict__ qb,   // (B,H,S,DK) bf16, roped
    const unsigned short* __restrict__ kbf,  // (B,KH,S,DK) bf16, roped
    const unsigned short* __restrict__ vT,   // (B,KH,DK,S) bf16
    unsigned short* __restrict__ ot)         // (B,S,H*DK) bf16
{
    __shared__ unsigned short Ks[2][64][72];
    __shared__ unsigned short Vs[2][64][72];
    __shared__ unsigned short Ps[4][32][72];

    const int tid = threadIdx.x;
    const int bx  = blockIdx.x;
    const int bh  = bx >> 4;
    const int b   = bh >> 4, h = bh & 15;
    const int kh  = h >> 2;
    const int jj  = bx & 15;
    const int q0  = jj * 128;

    const int wv   = tid >> 6;
    const int lane = tid & 63;
    const int n    = lane & 15;
    const int quad = lane >> 4;

    const unsigned short* qp =
        qb + ((long)(b * H_ + h) * S_ + q0 + wv * 32 + n) * DK_;
    bf16x8 qa[2][2];
    qa[0][0] = *(const bf16x8*)(qp + quad * 8);
    qa[0][1] = *(const bf16x8*)(qp + 32 + quad * 8);
    qa[1][0] = *(const bf16x8*)(qp + 16 * DK_ + quad * 8);
    qa[1][1] = *(const bf16x8*)(qp + 16 * DK_ + 32 + quad * 8);

    f32x4 O[2][4];
    #pragma unroll
    for (int i = 0; i < 2; ++i)
        #pragma unroll
        for (int dt = 0; dt < 4; ++dt) O[i][dt] = 0.0f;
    float mrun[2][4], lrun[2][4];
    #pragma unroll
    for (int i = 0; i < 2; ++i)
        #pragma unroll
        for (int r = 0; r < 4; ++r) { mrun[i][r] = -INFINITY; lrun[i][r] = 0.f; }

    const unsigned short* kbase = kbf + (long)(b * KH_ + kh) * S_ * DK_;
    const unsigned short* vbase = vT  + (long)(b * KH_ + kh) * DK_ * S_;

    const int ntiles = 2 * jj + 2;
    const int srow = tid >> 3;          // 0..31
    const int sc8  = (tid & 7) * 8;

    u32x4 kr0 = *(const u32x4*)(kbase + (long)srow * DK_ + sc8);
    u32x4 kr1 = *(const u32x4*)(kbase + (long)(32 + srow) * DK_ + sc8);
    u32x4 vr0 = *(const u32x4*)(vbase + (long)srow * S_ + sc8);
    u32x4 vr1 = *(const u32x4*)(vbase + (long)(32 + srow) * S_ + sc8);
    *(u32x4*)&Ks[0][srow][sc8]      = kr0;
    *(u32x4*)&Ks[0][32 + srow][sc8] = kr1;
    *(u32x4*)&Vs[0][srow][sc8]      = vr0;
    *(u32x4*)&Vs[0][32 + srow][sc8] = vr1;

    const float sfac = 0.125f * 1.44269504f;   // 1/sqrt(64) * log2(e)

    for (int u = 0; u < ntiles; ++u) {
        const int cur = u & 1;
        const int kb  = u * 64;
        __syncthreads();

        if (u + 1 < ntiles) {
            const int kbn = kb + 64;
            kr0 = *(const u32x4*)(kbase + (long)(kbn + srow) * DK_ + sc8);
            kr1 = *(const u32x4*)(kbase + (long)(kbn + 32 + srow) * DK_ + sc8);
            vr0 = *(const u32x4*)(vbase + (long)srow * S_ + kbn + sc8);
            vr1 = *(const u32x4*)(vbase + (long)(32 + srow) * S_ + kbn + sc8);
        }

        bf16x8 kf0[4], kf1[4];
        #pragma unroll
        for (int ct = 0; ct < 4; ++ct) {
            kf0[ct] = *(const bf16x8*)&Ks[cur][ct * 16 + n][quad * 8];
            kf1[ct] = *(const bf16x8*)&Ks[cur][ct * 16 + n][32 + quad * 8];
        }
        f32x4 sc[2][4];
        #pragma unroll
        for (int i = 0; i < 2; ++i)
            #pragma unroll
            for (int ct = 0; ct < 4; ++ct) {
                f32x4 c = 0.0f;
                c = __builtin_amdgcn_mfma_f32_16x16x32_bf16(qa[i][0], kf0[ct], c, 0, 0, 0);
                c = __builtin_amdgcn_mfma_f32_16x16x32_bf16(qa[i][1], kf1[ct], c, 0, 0, 0);
                sc[i][ct] = c;
            }

        const bool domask = (u >= 2 * jj);
        float cr[2][4];
        #pragma unroll
        for (int i = 0; i < 2; ++i) {
            const int rg = q0 + wv * 32 + i * 16 + quad * 4;
            #pragma unroll
            for (int r = 0; r < 4; ++r) {
                float mx = -INFINITY;
                #pragma unroll
                for (int ct = 0; ct < 4; ++ct) {
                    float s = sc[i][ct][r] * sfac;
                    if (domask) {
                        const int col = kb + ct * 16 + n;
                        s = (col <= rg + r) ? s : -INFINITY;
                    }
                    sc[i][ct][r] = s;
                    mx = fmaxf(mx, s);
                }
                mx = fmaxf(mx, __shfl_xor(mx, 1));
                mx = fmaxf(mx, __shfl_xor(mx, 2));
                mx = fmaxf(mx, __shfl_xor(mx, 4));
                mx = fmaxf(mx, __shfl_xor(mx, 8));
                const float mn = fmaxf(mrun[i][r], mx);
                const float c_ = exp2f(mrun[i][r] - mn);
                float rs = 0.f;
                #pragma unroll
                for (int ct = 0; ct < 4; ++ct) {
                    const float p = exp2f(sc[i][ct][r] - mn);
                    sc[i][ct][r] = p;
                    rs += p;
                }
                rs += __shfl_xor(rs, 1);
                rs += __shfl_xor(rs, 2);
                rs += __shfl_xor(rs, 4);
                rs += __shfl_xor(rs, 8);
                lrun[i][r] = lrun[i][r] * c_ + rs;
                mrun[i][r] = mn;
                cr[i][r] = c_;
            }
        }
        #pragma unroll
        for (int i = 0; i < 2; ++i)
            #pragma unroll
            for (int dt = 0; dt < 4; ++dt)
                #pragma unroll
                for (int r = 0; r < 4; ++r) O[i][dt][r] *= cr[i][r];

        #pragma unroll
        for (int i = 0; i < 2; ++i)
            #pragma unroll
            for (int ct = 0; ct < 4; ++ct)
                #pragma unroll
                for (int r = 0; r < 4; ++r)
                    Ps[wv][i * 16 + quad * 4 + r][ct * 16 + n] = f2bf(sc[i][ct][r]);
        bf16x8 pa[2][2];
        #pragma unroll
        for (int i = 0; i < 2; ++i) {
            pa[i][0] = *(const bf16x8*)&Ps[wv][i * 16 + n][quad * 8];
            pa[i][1] = *(const bf16x8*)&Ps[wv][i * 16 + n][32 + quad * 8];
        }

        #pragma unroll
        for (int dt = 0; dt < 4; ++dt) {
            const bf16x8 v0 = *(const bf16x8*)&Vs[cur][dt * 16 + n][quad * 8];
            const bf16x8 v1 = *(const bf16x8*)&Vs[cur][dt * 16 + n][32 + quad * 8];
            #pragma unroll
            for (int i = 0; i < 2; ++i) {
                O[i][dt] = __builtin_amdgcn_mfma_f32_16x16x32_bf16(pa[i][0], v0, O[i][dt], 0, 0, 0);
                O[i][dt] = __builtin_amdgcn_mfma_f32_16x16x32_bf16(pa[i][1], v1, O[i][dt], 0, 0, 0);
            }
        }

        if (u + 1 < ntiles) {
            const int nb = cur ^ 1;
            *(u32x4*)&Ks[nb][srow][sc8]      = kr0;
            *(u32x4*)&Ks[nb][32 + srow][sc8] = kr1;
            *(u32x4*)&Vs[nb][srow][sc8]      = vr0;
            *(u32x4*)&Vs[nb][32 + srow][sc8] = vr1;
        }
    }

    #pragma unroll
    for (int i = 0; i < 2; ++i) {
        const int rg = q0 + wv * 32 + i * 16 + quad * 4;
        #pragma unroll
        for (int r = 0; r < 4; ++r) {
            const float inv = 1.0f / lrun[i][r];
            unsigned short* op = ot + ((long)(b * S_ + rg + r) * H_ + h) * DK_;
            #pragma unroll
            for (int dt = 0; dt < 4; ++dt)
                op[dt * 16 + n] = f2bf(O[i][dt][r] * inv);
        }
    }
}

// ---------------------------------------------------------------------------
extern "C" void kernel_launch(void* const* d_in, const int* in_sizes, int n_in,
                              void* d_out, int out_size, void* d_ws, size_t ws_size,
                              hipStream_t stream)
{
    const float* x  = (const float*)d_in[0];
    const float* Wq = (const float*)d_in[2];
    const float* bq = (const float*)d_in[3];
    const float* Wk = (const float*)d_in[4];
    const float* bk = (const float*)d_in[5];
    const float* Wv = (const float*)d_in[6];
    const float* bv = (const float*)d_in[7];
    const float* Wo = (const float*)d_in[8];
    const float* bo = (const float*)d_in[9];
    float* out = (float*)d_out;

    // Workspace (bf16 elements): 34.6 MB total
    unsigned short* ws     = (unsigned short*)d_ws;
    unsigned short* xb     = ws;                  // 4194304
    unsigned short* qbuf   = xb + 4194304;        // 4194304  roped Q (B,H,S,DK)
    unsigned short* kbuf   = qbuf + 4194304;      // 1048576  roped K (B,KH,S,DK)
    unsigned short* vbuf   = kbuf + 1048576;      // 1048576  V^T (B,KH,DK,S)
    unsigned short* ob     = vbuf + 1048576;      // 4194304  attn out (B,S,H*DK)
    unsigned short* WqkvT  = ob + 4194304;        // 1572864  [1536 x 1024]
    unsigned short* WoT    = WqkvT + 1572864;     // 1048576

    const int M = B_ * S_;                        // 4096

    cast_bf16_kernel<<<(M * D_ / 8) / 256, 256, 0, stream>>>(x, xb, M * D_ / 8);
    transpose_cast_kernel<<<256, 256, 0, stream>>>(Wq, WqkvT,                1024, 1024);
    transpose_cast_kernel<<<64,  256, 0, stream>>>(Wk, WqkvT + 1024 * 1024, 1024, 256);
    transpose_cast_kernel<<<64,  256, 0, stream>>>(Wv, WqkvT + 1280 * 1024, 1024, 256);
    transpose_cast_kernel<<<256, 256, 0, stream>>>(Wo, WoT,                 1024, 1024);

    // Fused QKV projection + rope + V-transpose (LDS-staged, full-line stores)
    gemm_bt<128, 1><<<dim3(32, 12), 256, 0, stream>>>(
        xb, WqkvT, bq, bk, bv, nullptr, qbuf, kbuf, vbuf, M, 1536, D_);

    attn_mfma_kernel<<<B_ * H_ * (S_ / 128), 256, 0, stream>>>(qbuf, kbuf, vbuf, ob);

    // Output projection
    gemm_bt<64, 0><<<dim3(32, 16), 256, 0, stream>>>(
        ob, WoT, bo, nullptr, nullptr, out, nullptr, nullptr, nullptr, M, 1024, D_);
}

// Round 6
// 298.411 us; speedup vs baseline: 4.5959x; 1.3477x over previous
//
#include <hip/hip_runtime.h>
#include <math.h>

#define B_   2
#define S_   2048
#define D_   1024
#define H_   16
#define KH_  4
#define DK_  64

using bf16x8 = __attribute__((ext_vector_type(8))) short;
using f32x4  = __attribute__((ext_vector_type(4))) float;
using u32x4  = __attribute__((ext_vector_type(4))) unsigned int;

__device__ inline unsigned short f2bf(float f) {
    unsigned u = __float_as_uint(f);
    u += 0x7FFFu + ((u >> 16) & 1u);          // RNE
    return (unsigned short)(u >> 16);
}
__device__ inline float bf2f(unsigned short u) {
    return __uint_as_float(((unsigned)u) << 16);
}

// ---------------------------------------------------------------------------
// cast fp32 -> bf16, 8 elems/thread
// ---------------------------------------------------------------------------
__global__ __launch_bounds__(256) void cast_bf16_kernel(
    const float* __restrict__ in, unsigned short* __restrict__ out, int n8)
{
    const int i = blockIdx.x * 256 + threadIdx.x;
    if (i >= n8) return;
    f32x4 a = *(const f32x4*)(in + (long)i * 8);
    f32x4 b = *(const f32x4*)(in + (long)i * 8 + 4);
    bf16x8 o;
    o[0] = (short)f2bf(a[0]); o[1] = (short)f2bf(a[1]);
    o[2] = (short)f2bf(a[2]); o[3] = (short)f2bf(a[3]);
    o[4] = (short)f2bf(b[0]); o[5] = (short)f2bf(b[1]);
    o[6] = (short)f2bf(b[2]); o[7] = (short)f2bf(b[3]);
    *(bf16x8*)(out + (long)i * 8) = o;
}

// ---------------------------------------------------------------------------
// transpose + cast: in fp32 (R,C) -> out bf16 (C,R). 64x64 tiles.
// ---------------------------------------------------------------------------
__global__ __launch_bounds__(256) void transpose_cast_kernel(
    const float* __restrict__ in, unsigned short* __restrict__ out, int R, int C)
{
    __shared__ float T[64][65];
    const int bx = blockIdx.x;
    const int nr = R >> 6;
    const int r0 = (bx % nr) * 64;
    const int c0 = (bx / nr) * 64;
    const int t  = threadIdx.x;

    {
        const int r  = t >> 2;
        const int cq = (t & 3) * 16;
        const float* src = in + (long)(r0 + r) * C + c0 + cq;
        #pragma unroll
        for (int i = 0; i < 4; ++i) {
            f32x4 v = *(const f32x4*)(src + i * 4);
            T[r][cq + i * 4 + 0] = v[0];
            T[r][cq + i * 4 + 1] = v[1];
            T[r][cq + i * 4 + 2] = v[2];
            T[r][cq + i * 4 + 3] = v[3];
        }
    }
    __syncthreads();
    {
        const int c  = t >> 2;
        const int rq = (t & 3) * 16;
        bf16x8 p0, p1;
        #pragma unroll
        for (int i = 0; i < 8; ++i) {
            p0[i] = (short)f2bf(T[rq + i][c]);
            p1[i] = (short)f2bf(T[rq + 8 + i][c]);
        }
        unsigned short* dst = out + (long)(c0 + c) * R + r0 + rq;
        *(bf16x8*)dst       = p0;
        *(bf16x8*)(dst + 8) = p1;
    }
}

// ---------------------------------------------------------------------------
// QKV GEMM: qkvm[4096,1536] = xb[4096,1024] @ WqkvT[1536,1024]^T + bias,
// bf16 out, plain row-major (store pattern proven clean in round 3).
// 128x128 tile, BK=32, 4 waves (2x2), register-prefetch pipeline.
// ---------------------------------------------------------------------------
__global__ __launch_bounds__(256) void qkv_gemm_kernel(
    const unsigned short* __restrict__ A,     // [4096,1024]
    const unsigned short* __restrict__ Bt,    // [1536,1024]
    const float* __restrict__ bq,
    const float* __restrict__ bk,
    const float* __restrict__ bv,
    unsigned short* __restrict__ out)         // [4096,1536] bf16
{
    const int K = 1024, N = 1536;
    __shared__ unsigned short As[128][40];
    __shared__ unsigned short Bs[128][40];

    const int t  = threadIdx.x;
    const int m0 = blockIdx.x * 128;
    const int n0 = blockIdx.y * 128;

    const int w    = t >> 6;
    const int lane = t & 63;
    const int n    = lane & 15;
    const int quad = lane >> 4;
    const int wm   = (w >> 1) * 64;
    const int wn   = (w & 1) * 64;

    const int lr = t >> 2;
    const int lc = (t & 3) * 8;

    f32x4 acc[4][4];
    #pragma unroll
    for (int i = 0; i < 4; ++i)
        #pragma unroll
        for (int j = 0; j < 4; ++j) acc[i][j] = 0.0f;

    u32x4 ar0 = *(const u32x4*)&A [(long)(m0 + lr)      * K + lc];
    u32x4 ar1 = *(const u32x4*)&A [(long)(m0 + 64 + lr) * K + lc];
    u32x4 br0 = *(const u32x4*)&Bt[(long)(n0 + lr)      * K + lc];
    u32x4 br1 = *(const u32x4*)&Bt[(long)(n0 + 64 + lr) * K + lc];

    for (int k0 = 0; k0 < K; k0 += 32) {
        __syncthreads();
        *(u32x4*)&As[lr][lc]      = ar0;
        *(u32x4*)&As[lr + 64][lc] = ar1;
        *(u32x4*)&Bs[lr][lc]      = br0;
        *(u32x4*)&Bs[lr + 64][lc] = br1;
        __syncthreads();

        if (k0 + 32 < K) {
            ar0 = *(const u32x4*)&A [(long)(m0 + lr)      * K + k0 + 32 + lc];
            ar1 = *(const u32x4*)&A [(long)(m0 + 64 + lr) * K + k0 + 32 + lc];
            br0 = *(const u32x4*)&Bt[(long)(n0 + lr)      * K + k0 + 32 + lc];
            br1 = *(const u32x4*)&Bt[(long)(n0 + 64 + lr) * K + k0 + 32 + lc];
        }

        bf16x8 af[4], bfr[4];
        #pragma unroll
        for (int i = 0; i < 4; ++i) {
            af[i]  = *(const bf16x8*)&As[wm + i * 16 + n][quad * 8];
            bfr[i] = *(const bf16x8*)&Bs[wn + i * 16 + n][quad * 8];
        }
        #pragma unroll
        for (int mi = 0; mi < 4; ++mi)
            #pragma unroll
            for (int ni = 0; ni < 4; ++ni)
                acc[mi][ni] = __builtin_amdgcn_mfma_f32_16x16x32_bf16(
                    af[mi], bfr[ni], acc[mi][ni], 0, 0, 0);
    }

    #pragma unroll
    for (int mi = 0; mi < 4; ++mi) {
        #pragma unroll
        for (int r = 0; r < 4; ++r) {
            const int gm = m0 + wm + mi * 16 + quad * 4 + r;
            #pragma unroll
            for (int ni = 0; ni < 4; ++ni) {
                const int gn = n0 + wn + ni * 16 + n;
                const float b = (gn < 1024) ? bq[gn]
                              : (gn < 1280) ? bk[gn - 1024]
                                            : bv[gn - 1280];
                out[(long)gm * N + gn] = f2bf(acc[mi][ni][r] + b);
            }
        }
    }
}

// ---------------------------------------------------------------------------
// RoPE scatter: qkvm rows -> qbuf (B,H,S,DK) and kbuf (B,KH,S,DK), bf16.
// thread = (row m, head 0..19, 8-col chunk of d in [0,32))
// ---------------------------------------------------------------------------
__global__ __launch_bounds__(256) void rope_scatter_kernel(
    const unsigned short* __restrict__ qkvm,  // [4096,1536]
    unsigned short* __restrict__ qbuf,
    unsigned short* __restrict__ kbuf)
{
    const int idx = blockIdx.x * 256 + threadIdx.x;   // 4096*80 total
    const int m   = idx / 80;
    const int rem = idx - m * 80;
    const int h20 = rem >> 2;
    const int d0  = (rem & 3) * 8;

    const int s  = m & (S_ - 1);
    const int bb = m >> 11;
    const int col0 = (h20 < 16) ? h20 * 64 + d0 : 1024 + (h20 - 16) * 64 + d0;

    const bf16x8 x1v = *(const bf16x8*)(qkvm + (long)m * 1536 + col0);
    const bf16x8 x2v = *(const bf16x8*)(qkvm + (long)m * 1536 + col0 + 32);
    bf16x8 o1, o2;
    #pragma unroll
    for (int j = 0; j < 8; ++j) {
        const int d = d0 + j;
        const float theta = exp2f(-(float)d * (13.287712379549449f / 32.0f));
        const float f = (float)s * theta;
        const float c = cosf(f), sn = sinf(f);
        const float x1 = bf2f((unsigned short)x1v[j]);
        const float x2 = bf2f((unsigned short)x2v[j]);
        o1[j] = (short)f2bf(x1 * c - x2 * sn);
        o2[j] = (short)f2bf(x2 * c + x1 * sn);
    }
    unsigned short* dst = (h20 < 16)
        ? qbuf + ((long)(bb * H_ + h20) * S_ + s) * DK_ + d0
        : kbuf + ((long)(bb * KH_ + (h20 - 16)) * S_ + s) * DK_ + d0;
    *(bf16x8*)dst        = o1;
    *(bf16x8*)(dst + 32) = o2;
}

// ---------------------------------------------------------------------------
// V transpose: qkvm cols 1280..1535 -> vbuf (B,KH,DK,S) bf16. 64x64 tiles.
// ---------------------------------------------------------------------------
__global__ __launch_bounds__(256) void vT_kernel(
    const unsigned short* __restrict__ qkvm,
    unsigned short* __restrict__ vbuf)
{
    __shared__ unsigned short T[64][72];
    const int bx  = blockIdx.x;              // 8 heads * 32 s-tiles
    const int bkh = bx >> 5;
    const int s0  = (bx & 31) * 64;
    const int t   = threadIdx.x;

    {
        const int s  = t >> 2;
        const int dq = (t & 3) * 16;
        const unsigned short* src =
            qkvm + (long)((bkh >> 2) * S_ + s0 + s) * 1536 + 1280 + (bkh & 3) * 64 + dq;
        *(bf16x8*)&T[s][dq]     = *(const bf16x8*)src;
        *(bf16x8*)&T[s][dq + 8] = *(const bf16x8*)(src + 8);
    }
    __syncthreads();
    {
        const int d  = t >> 2;
        const int sq = (t & 3) * 16;
        bf16x8 p0, p1;
        #pragma unroll
        for (int i = 0; i < 8; ++i) {
            p0[i] = (short)T[sq + i][d];
            p1[i] = (short)T[sq + 8 + i][d];
        }
        unsigned short* dst = vbuf + ((long)bkh * DK_ + d) * S_ + s0 + sq;
        *(bf16x8*)dst       = p0;
        *(bf16x8*)(dst + 8) = p1;
    }
}

// ---------------------------------------------------------------------------
// bf16 MFMA causal flash attention (round-5 structure, renamed).
// ---------------------------------------------------------------------------
__global__ __launch_bounds__(256) void attn_kernel(
    const unsigned short* __restrict__ qb,   // (B,H,S,DK)
    const unsigned short* __restrict__ kbf,  // (B,KH,S,DK)
    const unsigned short* __restrict__ vT,   // (B,KH,DK,S)
    unsigned short* __restrict__ ot)         // (B,S,H*DK)
{
    __shared__ unsigned short Ks[2][64][72];
    __shared__ unsigned short Vs[2][64][72];
    __shared__ unsigned short Ps[4][32][72];

    const int tid = threadIdx.x;
    const int bx  = blockIdx.x;
    const int bh  = bx >> 4;
    const int b   = bh >> 4, h = bh & 15;
    const int kh  = h >> 2;
    const int jj  = bx & 15;
    const int q0  = jj * 128;

    const int wv   = tid >> 6;
    const int lane = tid & 63;
    const int n    = lane & 15;
    const int quad = lane >> 4;

    const unsigned short* qp =
        qb + ((long)(b * H_ + h) * S_ + q0 + wv * 32 + n) * DK_;
    bf16x8 qa[2][2];
    qa[0][0] = *(const bf16x8*)(qp + quad * 8);
    qa[0][1] = *(const bf16x8*)(qp + 32 + quad * 8);
    qa[1][0] = *(const bf16x8*)(qp + 16 * DK_ + quad * 8);
    qa[1][1] = *(const bf16x8*)(qp + 16 * DK_ + 32 + quad * 8);

    f32x4 O[2][4];
    #pragma unroll
    for (int i = 0; i < 2; ++i)
        #pragma unroll
        for (int dt = 0; dt < 4; ++dt) O[i][dt] = 0.0f;
    float mrun[2][4], lrun[2][4];
    #pragma unroll
    for (int i = 0; i < 2; ++i)
        #pragma unroll
        for (int r = 0; r < 4; ++r) { mrun[i][r] = -INFINITY; lrun[i][r] = 0.f; }

    const unsigned short* kbase = kbf + (long)(b * KH_ + kh) * S_ * DK_;
    const unsigned short* vbase = vT  + (long)(b * KH_ + kh) * DK_ * S_;

    const int ntiles = 2 * jj + 2;
    const int srow = tid >> 3;
    const int sc8  = (tid & 7) * 8;

    u32x4 kr0 = *(const u32x4*)(kbase + (long)srow * DK_ + sc8);
    u32x4 kr1 = *(const u32x4*)(kbase + (long)(32 + srow) * DK_ + sc8);
    u32x4 vr0 = *(const u32x4*)(vbase + (long)srow * S_ + sc8);
    u32x4 vr1 = *(const u32x4*)(vbase + (long)(32 + srow) * S_ + sc8);
    *(u32x4*)&Ks[0][srow][sc8]      = kr0;
    *(u32x4*)&Ks[0][32 + srow][sc8] = kr1;
    *(u32x4*)&Vs[0][srow][sc8]      = vr0;
    *(u32x4*)&Vs[0][32 + srow][sc8] = vr1;

    const float sfac = 0.125f * 1.44269504f;

    for (int u = 0; u < ntiles; ++u) {
        const int cur = u & 1;
        const int kb  = u * 64;
        __syncthreads();

        if (u + 1 < ntiles) {
            const int kbn = kb + 64;
            kr0 = *(const u32x4*)(kbase + (long)(kbn + srow) * DK_ + sc8);
            kr1 = *(const u32x4*)(kbase + (long)(kbn + 32 + srow) * DK_ + sc8);
            vr0 = *(const u32x4*)(vbase + (long)srow * S_ + kbn + sc8);
            vr1 = *(const u32x4*)(vbase + (long)(32 + srow) * S_ + kbn + sc8);
        }

        bf16x8 kf0[4], kf1[4];
        #pragma unroll
        for (int ct = 0; ct < 4; ++ct) {
            kf0[ct] = *(const bf16x8*)&Ks[cur][ct * 16 + n][quad * 8];
            kf1[ct] = *(const bf16x8*)&Ks[cur][ct * 16 + n][32 + quad * 8];
        }
        f32x4 sc[2][4];
        #pragma unroll
        for (int i = 0; i < 2; ++i)
            #pragma unroll
            for (int ct = 0; ct < 4; ++ct) {
                f32x4 c = 0.0f;
                c = __builtin_amdgcn_mfma_f32_16x16x32_bf16(qa[i][0], kf0[ct], c, 0, 0, 0);
                c = __builtin_amdgcn_mfma_f32_16x16x32_bf16(qa[i][1], kf1[ct], c, 0, 0, 0);
                sc[i][ct] = c;
            }

        const bool domask = (u >= 2 * jj);
        float cr[2][4];
        #pragma unroll
        for (int i = 0; i < 2; ++i) {
            const int rg = q0 + wv * 32 + i * 16 + quad * 4;
            #pragma unroll
            for (int r = 0; r < 4; ++r) {
                float mx = -INFINITY;
                #pragma unroll
                for (int ct = 0; ct < 4; ++ct) {
                    float s = sc[i][ct][r] * sfac;
                    if (domask) {
                        const int col = kb + ct * 16 + n;
                        s = (col <= rg + r) ? s : -INFINITY;
                    }
                    sc[i][ct][r] = s;
                    mx = fmaxf(mx, s);
                }
                mx = fmaxf(mx, __shfl_xor(mx, 1));
                mx = fmaxf(mx, __shfl_xor(mx, 2));
                mx = fmaxf(mx, __shfl_xor(mx, 4));
                mx = fmaxf(mx, __shfl_xor(mx, 8));
                const float mn = fmaxf(mrun[i][r], mx);
                const float c_ = exp2f(mrun[i][r] - mn);
                float rs = 0.f;
                #pragma unroll
                for (int ct = 0; ct < 4; ++ct) {
                    const float p = exp2f(sc[i][ct][r] - mn);
                    sc[i][ct][r] = p;
                    rs += p;
                }
                rs += __shfl_xor(rs, 1);
                rs += __shfl_xor(rs, 2);
                rs += __shfl_xor(rs, 4);
                rs += __shfl_xor(rs, 8);
                lrun[i][r] = lrun[i][r] * c_ + rs;
                mrun[i][r] = mn;
                cr[i][r] = c_;
            }
        }
        #pragma unroll
        for (int i = 0; i < 2; ++i)
            #pragma unroll
            for (int dt = 0; dt < 4; ++dt)
                #pragma unroll
                for (int r = 0; r < 4; ++r) O[i][dt][r] *= cr[i][r];

        #pragma unroll
        for (int i = 0; i < 2; ++i)
            #pragma unroll
            for (int ct = 0; ct < 4; ++ct)
                #pragma unroll
                for (int r = 0; r < 4; ++r)
                    Ps[wv][i * 16 + quad * 4 + r][ct * 16 + n] = f2bf(sc[i][ct][r]);
        bf16x8 pa[2][2];
        #pragma unroll
        for (int i = 0; i < 2; ++i) {
            pa[i][0] = *(const bf16x8*)&Ps[wv][i * 16 + n][quad * 8];
            pa[i][1] = *(const bf16x8*)&Ps[wv][i * 16 + n][32 + quad * 8];
        }

        #pragma unroll
        for (int dt = 0; dt < 4; ++dt) {
            const bf16x8 v0 = *(const bf16x8*)&Vs[cur][dt * 16 + n][quad * 8];
            const bf16x8 v1 = *(const bf16x8*)&Vs[cur][dt * 16 + n][32 + quad * 8];
            #pragma unroll
            for (int i = 0; i < 2; ++i) {
                O[i][dt] = __builtin_amdgcn_mfma_f32_16x16x32_bf16(pa[i][0], v0, O[i][dt], 0, 0, 0);
                O[i][dt] = __builtin_amdgcn_mfma_f32_16x16x32_bf16(pa[i][1], v1, O[i][dt], 0, 0, 0);
            }
        }

        if (u + 1 < ntiles) {
            const int nb = cur ^ 1;
            *(u32x4*)&Ks[nb][srow][sc8]      = kr0;
            *(u32x4*)&Ks[nb][32 + srow][sc8] = kr1;
            *(u32x4*)&Vs[nb][srow][sc8]      = vr0;
            *(u32x4*)&Vs[nb][32 + srow][sc8] = vr1;
        }
    }

    #pragma unroll
    for (int i = 0; i < 2; ++i) {
        const int rg = q0 + wv * 32 + i * 16 + quad * 4;
        #pragma unroll
        for (int r = 0; r < 4; ++r) {
            const float inv = 1.0f / lrun[i][r];
            unsigned short* op = ot + ((long)(b * S_ + rg + r) * H_ + h) * DK_;
            #pragma unroll
            for (int dt = 0; dt < 4; ++dt)
                op[dt * 16 + n] = f2bf(O[i][dt][r] * inv);
        }
    }
}

// ---------------------------------------------------------------------------
// Output projection: out[4096,1024] fp32 = ob[4096,1024] @ WoT[1024,1024]^T + bo
// 128x64 tile, BK=32, 4 waves (2x2 of 64x32), register-prefetch pipeline.
// ---------------------------------------------------------------------------
__global__ __launch_bounds__(256) void oproj_gemm_kernel(
    const unsigned short* __restrict__ A,
    const unsigned short* __restrict__ Bt,
    const float* __restrict__ bias,
    float* __restrict__ out)
{
    const int K = 1024, N = 1024;
    __shared__ unsigned short As[128][40];
    __shared__ unsigned short Bs[64][40];

    const int t  = threadIdx.x;
    const int m0 = blockIdx.x * 128;
    const int n0 = blockIdx.y * 64;

    const int w    = t >> 6;
    const int lane = t & 63;
    const int n    = lane & 15;
    const int quad = lane >> 4;
    const int wm   = (w >> 1) * 64;
    const int wn   = (w & 1) * 32;

    const int lr = t >> 2;
    const int lc = (t & 3) * 8;

    f32x4 acc[4][2];
    #pragma unroll
    for (int i = 0; i < 4; ++i)
        #pragma unroll
        for (int j = 0; j < 2; ++j) acc[i][j] = 0.0f;

    u32x4 ar0 = *(const u32x4*)&A [(long)(m0 + lr)      * K + lc];
    u32x4 ar1 = *(const u32x4*)&A [(long)(m0 + 64 + lr) * K + lc];
    u32x4 br0 = *(const u32x4*)&Bt[(long)(n0 + lr)      * K + lc];

    for (int k0 = 0; k0 < K; k0 += 32) {
        __syncthreads();
        *(u32x4*)&As[lr][lc]      = ar0;
        *(u32x4*)&As[lr + 64][lc] = ar1;
        if (lr < 64) *(u32x4*)&Bs[lr][lc] = br0;
        __syncthreads();

        if (k0 + 32 < K) {
            ar0 = *(const u32x4*)&A [(long)(m0 + lr)      * K + k0 + 32 + lc];
            ar1 = *(const u32x4*)&A [(long)(m0 + 64 + lr) * K + k0 + 32 + lc];
            br0 = *(const u32x4*)&Bt[(long)(n0 + lr)      * K + k0 + 32 + lc];
        }

        bf16x8 af[4], bfr[2];
        #pragma unroll
        for (int i = 0; i < 4; ++i)
            af[i] = *(const bf16x8*)&As[wm + i * 16 + n][quad * 8];
        #pragma unroll
        for (int j = 0; j < 2; ++j)
            bfr[j] = *(const bf16x8*)&Bs[wn + j * 16 + n][quad * 8];
        #pragma unroll
        for (int mi = 0; mi < 4; ++mi)
            #pragma unroll
            for (int ni = 0; ni < 2; ++ni)
                acc[mi][ni] = __builtin_amdgcn_mfma_f32_16x16x32_bf16(
                    af[mi], bfr[ni], acc[mi][ni], 0, 0, 0);
    }

    #pragma unroll
    for (int mi = 0; mi < 4; ++mi) {
        #pragma unroll
        for (int r = 0; r < 4; ++r) {
            const int gm = m0 + wm + mi * 16 + quad * 4 + r;
            #pragma unroll
            for (int ni = 0; ni < 2; ++ni) {
                const int gn = n0 + wn + ni * 16 + n;
                out[(long)gm * N + gn] = acc[mi][ni][r] + bias[gn];
            }
        }
    }
}

// ---------------------------------------------------------------------------
extern "C" void kernel_launch(void* const* d_in, const int* in_sizes, int n_in,
                              void* d_out, int out_size, void* d_ws, size_t ws_size,
                              hipStream_t stream)
{
    const float* x  = (const float*)d_in[0];
    const float* Wq = (const float*)d_in[2];
    const float* bq = (const float*)d_in[3];
    const float* Wk = (const float*)d_in[4];
    const float* bk = (const float*)d_in[5];
    const float* Wv = (const float*)d_in[6];
    const float* bv = (const float*)d_in[7];
    const float* Wo = (const float*)d_in[8];
    const float* bo = (const float*)d_in[9];
    float* out = (float*)d_out;

    // Workspace (bf16 shorts), ~38.8 MB. ob aliases qkvm (dead after rope/vT).
    unsigned short* ws    = (unsigned short*)d_ws;
    unsigned short* xb    = ws;                   // 4194304
    unsigned short* qkvm  = xb + 4194304;         // 6291456  [4096,1536]
    unsigned short* qbuf  = qkvm + 6291456;       // 4194304
    unsigned short* kbuf  = qbuf + 4194304;       // 1048576
    unsigned short* vbuf  = kbuf + 1048576;       // 1048576
    unsigned short* WqkvT = vbuf + 1048576;       // 1572864
    unsigned short* WoT   = WqkvT + 1572864;      // 1048576
    unsigned short* ob    = qkvm;                 // alias

    const int M = B_ * S_;                        // 4096

    cast_bf16_kernel<<<(M * D_ / 8) / 256, 256, 0, stream>>>(x, xb, M * D_ / 8);
    transpose_cast_kernel<<<256, 256, 0, stream>>>(Wq, WqkvT,                1024, 1024);
    transpose_cast_kernel<<<64,  256, 0, stream>>>(Wk, WqkvT + 1024 * 1024, 1024, 256);
    transpose_cast_kernel<<<64,  256, 0, stream>>>(Wv, WqkvT + 1280 * 1024, 1024, 256);
    transpose_cast_kernel<<<256, 256, 0, stream>>>(Wo, WoT,                 1024, 1024);

    qkv_gemm_kernel<<<dim3(32, 12), 256, 0, stream>>>(xb, WqkvT, bq, bk, bv, qkvm);
    rope_scatter_kernel<<<(M * 80) / 256, 256, 0, stream>>>(qkvm, qbuf, kbuf);
    vT_kernel<<<B_ * KH_ * (S_ / 64), 256, 0, stream>>>(qkvm, vbuf);

    attn_kernel<<<B_ * H_ * (S_ / 128), 256, 0, stream>>>(qbuf, kbuf, vbuf, ob);

    oproj_gemm_kernel<<<dim3(32, 16), 256, 0, stream>>>(ob, WoT, bo, out);
}

// Round 7
// 276.781 us; speedup vs baseline: 4.9550x; 1.0781x over previous
//
#include <hip/hip_runtime.h>
#include <math.h>

#define B_   2
#define S_   2048
#define D_   1024
#define H_   16
#define KH_  4
#define DK_  64

using bf16x8 = __attribute__((ext_vector_type(8))) short;
using bf16x4 = __attribute__((ext_vector_type(4))) short;
using f32x4  = __attribute__((ext_vector_type(4))) float;
using u32x4  = __attribute__((ext_vector_type(4))) unsigned int;

__device__ inline unsigned short f2bf(float f) {
    unsigned u = __float_as_uint(f);
    u += 0x7FFFu + ((u >> 16) & 1u);          // RNE
    return (unsigned short)(u >> 16);
}
__device__ inline float bf2f(unsigned short u) {
    return __uint_as_float(((unsigned)u) << 16);
}

// ---------------------------------------------------------------------------
// cast fp32 -> bf16, 8 elems/thread
// ---------------------------------------------------------------------------
__global__ __launch_bounds__(256) void cast_bf16_kernel(
    const float* __restrict__ in, unsigned short* __restrict__ out, int n8)
{
    const int i = blockIdx.x * 256 + threadIdx.x;
    if (i >= n8) return;
    f32x4 a = *(const f32x4*)(in + (long)i * 8);
    f32x4 b = *(const f32x4*)(in + (long)i * 8 + 4);
    bf16x8 o;
    o[0] = (short)f2bf(a[0]); o[1] = (short)f2bf(a[1]);
    o[2] = (short)f2bf(a[2]); o[3] = (short)f2bf(a[3]);
    o[4] = (short)f2bf(b[0]); o[5] = (short)f2bf(b[1]);
    o[6] = (short)f2bf(b[2]); o[7] = (short)f2bf(b[3]);
    *(bf16x8*)(out + (long)i * 8) = o;
}

// ---------------------------------------------------------------------------
// transpose + cast: in fp32 (R,C) -> out bf16 (C,R). 64x64 tiles.
// ---------------------------------------------------------------------------
__global__ __launch_bounds__(256) void transpose_cast_kernel(
    const float* __restrict__ in, unsigned short* __restrict__ out, int R, int C)
{
    __shared__ float T[64][65];
    const int bx = blockIdx.x;
    const int nr = R >> 6;
    const int r0 = (bx % nr) * 64;
    const int c0 = (bx / nr) * 64;
    const int t  = threadIdx.x;

    {
        const int r  = t >> 2;
        const int cq = (t & 3) * 16;
        const float* src = in + (long)(r0 + r) * C + c0 + cq;
        #pragma unroll
        for (int i = 0; i < 4; ++i) {
            f32x4 v = *(const f32x4*)(src + i * 4);
            T[r][cq + i * 4 + 0] = v[0];
            T[r][cq + i * 4 + 1] = v[1];
            T[r][cq + i * 4 + 2] = v[2];
            T[r][cq + i * 4 + 3] = v[3];
        }
    }
    __syncthreads();
    {
        const int c  = t >> 2;
        const int rq = (t & 3) * 16;
        bf16x8 p0, p1;
        #pragma unroll
        for (int i = 0; i < 8; ++i) {
            p0[i] = (short)f2bf(T[rq + i][c]);
            p1[i] = (short)f2bf(T[rq + 8 + i][c]);
        }
        unsigned short* dst = out + (long)(c0 + c) * R + r0 + rq;
        *(bf16x8*)dst       = p0;
        *(bf16x8*)(dst + 8) = p1;
    }
}

// ---------------------------------------------------------------------------
// QKV GEMM: qkvm[4096,1536] = xb[4096,1024] @ WqkvT[1536,1024]^T + bias,
// bf16 out, plain row-major. 128x128 tile, BK=32, 4 waves (2x2).
// ---------------------------------------------------------------------------
__global__ __launch_bounds__(256) void qkv_gemm_kernel(
    const unsigned short* __restrict__ A,     // [4096,1024]
    const unsigned short* __restrict__ Bt,    // [1536,1024]
    const float* __restrict__ bq,
    const float* __restrict__ bk,
    const float* __restrict__ bv,
    unsigned short* __restrict__ out)         // [4096,1536] bf16
{
    const int K = 1024, N = 1536;
    __shared__ unsigned short As[128][40];
    __shared__ unsigned short Bs[128][40];

    const int t  = threadIdx.x;
    const int m0 = blockIdx.x * 128;
    const int n0 = blockIdx.y * 128;

    const int w    = t >> 6;
    const int lane = t & 63;
    const int n    = lane & 15;
    const int quad = lane >> 4;
    const int wm   = (w >> 1) * 64;
    const int wn   = (w & 1) * 64;

    const int lr = t >> 2;
    const int lc = (t & 3) * 8;

    f32x4 acc[4][4];
    #pragma unroll
    for (int i = 0; i < 4; ++i)
        #pragma unroll
        for (int j = 0; j < 4; ++j) acc[i][j] = 0.0f;

    u32x4 ar0 = *(const u32x4*)&A [(long)(m0 + lr)      * K + lc];
    u32x4 ar1 = *(const u32x4*)&A [(long)(m0 + 64 + lr) * K + lc];
    u32x4 br0 = *(const u32x4*)&Bt[(long)(n0 + lr)      * K + lc];
    u32x4 br1 = *(const u32x4*)&Bt[(long)(n0 + 64 + lr) * K + lc];

    for (int k0 = 0; k0 < K; k0 += 32) {
        __syncthreads();
        *(u32x4*)&As[lr][lc]      = ar0;
        *(u32x4*)&As[lr + 64][lc] = ar1;
        *(u32x4*)&Bs[lr][lc]      = br0;
        *(u32x4*)&Bs[lr + 64][lc] = br1;
        __syncthreads();

        if (k0 + 32 < K) {
            ar0 = *(const u32x4*)&A [(long)(m0 + lr)      * K + k0 + 32 + lc];
            ar1 = *(const u32x4*)&A [(long)(m0 + 64 + lr) * K + k0 + 32 + lc];
            br0 = *(const u32x4*)&Bt[(long)(n0 + lr)      * K + k0 + 32 + lc];
            br1 = *(const u32x4*)&Bt[(long)(n0 + 64 + lr) * K + k0 + 32 + lc];
        }

        bf16x8 af[4], bfr[4];
        #pragma unroll
        for (int i = 0; i < 4; ++i) {
            af[i]  = *(const bf16x8*)&As[wm + i * 16 + n][quad * 8];
            bfr[i] = *(const bf16x8*)&Bs[wn + i * 16 + n][quad * 8];
        }
        #pragma unroll
        for (int mi = 0; mi < 4; ++mi)
            #pragma unroll
            for (int ni = 0; ni < 4; ++ni)
                acc[mi][ni] = __builtin_amdgcn_mfma_f32_16x16x32_bf16(
                    af[mi], bfr[ni], acc[mi][ni], 0, 0, 0);
    }

    #pragma unroll
    for (int mi = 0; mi < 4; ++mi) {
        #pragma unroll
        for (int r = 0; r < 4; ++r) {
            const int gm = m0 + wm + mi * 16 + quad * 4 + r;
            #pragma unroll
            for (int ni = 0; ni < 4; ++ni) {
                const int gn = n0 + wn + ni * 16 + n;
                const float b = (gn < 1024) ? bq[gn]
                              : (gn < 1280) ? bk[gn - 1024]
                                            : bv[gn - 1280];
                out[(long)gm * N + gn] = f2bf(acc[mi][ni][r] + b);
            }
        }
    }
}

// ---------------------------------------------------------------------------
// RoPE scatter: qkvm rows -> qbuf (B,H,S,DK) and kbuf (B,KH,S,DK), bf16.
// ---------------------------------------------------------------------------
__global__ __launch_bounds__(256) void rope_scatter_kernel(
    const unsigned short* __restrict__ qkvm,  // [4096,1536]
    unsigned short* __restrict__ qbuf,
    unsigned short* __restrict__ kbuf)
{
    const int idx = blockIdx.x * 256 + threadIdx.x;   // 4096*80 total
    const int m   = idx / 80;
    const int rem = idx - m * 80;
    const int h20 = rem >> 2;
    const int d0  = (rem & 3) * 8;

    const int s  = m & (S_ - 1);
    const int bb = m >> 11;
    const int col0 = (h20 < 16) ? h20 * 64 + d0 : 1024 + (h20 - 16) * 64 + d0;

    const bf16x8 x1v = *(const bf16x8*)(qkvm + (long)m * 1536 + col0);
    const bf16x8 x2v = *(const bf16x8*)(qkvm + (long)m * 1536 + col0 + 32);
    bf16x8 o1, o2;
    #pragma unroll
    for (int j = 0; j < 8; ++j) {
        const int d = d0 + j;
        const float theta = exp2f(-(float)d * (13.287712379549449f / 32.0f));
        const float f = (float)s * theta;
        const float c = cosf(f), sn = sinf(f);
        const float x1 = bf2f((unsigned short)x1v[j]);
        const float x2 = bf2f((unsigned short)x2v[j]);
        o1[j] = (short)f2bf(x1 * c - x2 * sn);
        o2[j] = (short)f2bf(x2 * c + x1 * sn);
    }
    unsigned short* dst = (h20 < 16)
        ? qbuf + ((long)(bb * H_ + h20) * S_ + s) * DK_ + d0
        : kbuf + ((long)(bb * KH_ + (h20 - 16)) * S_ + s) * DK_ + d0;
    *(bf16x8*)dst        = o1;
    *(bf16x8*)(dst + 32) = o2;
}

// ---------------------------------------------------------------------------
// V transpose: qkvm cols 1280..1535 -> vbuf (B,KH,DK,S) bf16. 64x64 tiles.
// ---------------------------------------------------------------------------
__global__ __launch_bounds__(256) void vT_kernel(
    const unsigned short* __restrict__ qkvm,
    unsigned short* __restrict__ vbuf)
{
    __shared__ unsigned short T[64][72];
    const int bx  = blockIdx.x;
    const int bkh = bx >> 5;
    const int s0  = (bx & 31) * 64;
    const int t   = threadIdx.x;

    {
        const int s  = t >> 2;
        const int dq = (t & 3) * 16;
        const unsigned short* src =
            qkvm + (long)((bkh >> 2) * S_ + s0 + s) * 1536 + 1280 + (bkh & 3) * 64 + dq;
        *(bf16x8*)&T[s][dq]     = *(const bf16x8*)src;
        *(bf16x8*)&T[s][dq + 8] = *(const bf16x8*)(src + 8);
    }
    __syncthreads();
    {
        const int d  = t >> 2;
        const int sq = (t & 3) * 16;
        bf16x8 p0, p1;
        #pragma unroll
        for (int i = 0; i < 8; ++i) {
            p0[i] = (short)T[sq + i][d];
            p1[i] = (short)T[sq + 8 + i][d];
        }
        unsigned short* dst = vbuf + ((long)bkh * DK_ + d) * S_ + s0 + sq;
        *(bf16x8*)dst       = p0;
        *(bf16x8*)(dst + 8) = p1;
    }
}

// ---------------------------------------------------------------------------
// bf16 MFMA causal flash attention, v3: TRANSPOSED scores.
// S^T = K @ Q^T  (operand swap; A/B frags share per-lane indexing), so each
// lane owns one query COLUMN: 16 key-scores in registers. Row max/sum =
// in-lane tree + 2 shuffles (xor16/xor32), replacing 64 depth-4 shuffles
// per tile (round-6 latency bottleneck). O accumulates transposed
// (O^T = V^T @ P^T); epilogue transposes via LDS, coalesced stores.
// Balanced mapping: blocks g and g+256 get q-tiles jj and 15-jj.
// ---------------------------------------------------------------------------
__global__ __launch_bounds__(256) void attn_kernel(
    const unsigned short* __restrict__ qb,   // (B,H,S,DK)
    const unsigned short* __restrict__ kbf,  // (B,KH,S,DK)
    const unsigned short* __restrict__ vT,   // (B,KH,DK,S)
    unsigned short* __restrict__ ot)         // (B,S,H*DK)
{
    __shared__ unsigned short Ks[2][64][72];
    __shared__ unsigned short Vs[2][64][72];
    __shared__ unsigned short Ps[4][32][72]; // per-wave P^T / O^T scratch

    const int tid = threadIdx.x;
    const int bx  = blockIdx.x;
    // balanced mapping: (g, g+256) -> same (jj, 15-jj) pair
    const int half = bx >> 8;
    const int rr   = bx & 255;
    const int bh   = (rr >> 4) | (half << 4);
    const int jjr  = rr & 15;
    const int jj   = half ? (15 - jjr) : jjr;
    const int b    = bh >> 4, h = bh & 15;
    const int kh   = h >> 2;
    const int q0   = jj * 128;

    const int wv   = tid >> 6;
    const int lane = tid & 63;
    const int n    = lane & 15;
    const int quad = lane >> 4;

    // Q fragments (used as B-operand): lane n -> query q0 + wv*32 + i*16 + n
    const unsigned short* qp =
        qb + ((long)(b * H_ + h) * S_ + q0 + wv * 32 + n) * DK_;
    bf16x8 qa[2][2];
    qa[0][0] = *(const bf16x8*)(qp + quad * 8);
    qa[0][1] = *(const bf16x8*)(qp + 32 + quad * 8);
    qa[1][0] = *(const bf16x8*)(qp + 16 * DK_ + quad * 8);
    qa[1][1] = *(const bf16x8*)(qp + 16 * DK_ + 32 + quad * 8);

    f32x4 O[2][4];                    // O^T[d = dt*16+quad*4+r][q = i*16+n]
    #pragma unroll
    for (int i = 0; i < 2; ++i)
        #pragma unroll
        for (int dt = 0; dt < 4; ++dt) O[i][dt] = 0.0f;
    float mrun[2] = {-INFINITY, -INFINITY};
    float lrun[2] = {0.f, 0.f};

    const unsigned short* kbase = kbf + (long)(b * KH_ + kh) * S_ * DK_;
    const unsigned short* vbase = vT  + (long)(b * KH_ + kh) * DK_ * S_;

    const int ntiles = 2 * jj + 2;
    const int srow = tid >> 3;
    const int sc8  = (tid & 7) * 8;

    u32x4 kr0 = *(const u32x4*)(kbase + (long)srow * DK_ + sc8);
    u32x4 kr1 = *(const u32x4*)(kbase + (long)(32 + srow) * DK_ + sc8);
    u32x4 vr0 = *(const u32x4*)(vbase + (long)srow * S_ + sc8);
    u32x4 vr1 = *(const u32x4*)(vbase + (long)(32 + srow) * S_ + sc8);
    *(u32x4*)&Ks[0][srow][sc8]      = kr0;
    *(u32x4*)&Ks[0][32 + srow][sc8] = kr1;
    *(u32x4*)&Vs[0][srow][sc8]      = vr0;
    *(u32x4*)&Vs[0][32 + srow][sc8] = vr1;

    const float sfac = 0.125f * 1.44269504f;   // 1/sqrt(64) * log2(e)

    for (int u = 0; u < ntiles; ++u) {
        const int cur = u & 1;
        const int kb  = u * 64;
        __syncthreads();

        if (u + 1 < ntiles) {
            const int kbn = kb + 64;
            kr0 = *(const u32x4*)(kbase + (long)(kbn + srow) * DK_ + sc8);
            kr1 = *(const u32x4*)(kbase + (long)(kbn + 32 + srow) * DK_ + sc8);
            vr0 = *(const u32x4*)(vbase + (long)srow * S_ + kbn + sc8);
            vr1 = *(const u32x4*)(vbase + (long)(32 + srow) * S_ + kbn + sc8);
        }

        // ---- S^T = K @ Q^T : C[key][query] ----
        bf16x8 kf0[4], kf1[4];
        #pragma unroll
        for (int ct = 0; ct < 4; ++ct) {
            kf0[ct] = *(const bf16x8*)&Ks[cur][ct * 16 + n][quad * 8];
            kf1[ct] = *(const bf16x8*)&Ks[cur][ct * 16 + n][32 + quad * 8];
        }
        f32x4 sc[2][4];                // [i][ct]: key = kb+ct*16+quad*4+r, q = i*16+n
        #pragma unroll
        for (int i = 0; i < 2; ++i)
            #pragma unroll
            for (int ct = 0; ct < 4; ++ct) {
                f32x4 c = 0.0f;
                c = __builtin_amdgcn_mfma_f32_16x16x32_bf16(kf0[ct], qa[i][0], c, 0, 0, 0);
                c = __builtin_amdgcn_mfma_f32_16x16x32_bf16(kf1[ct], qa[i][1], c, 0, 0, 0);
                sc[i][ct] = c;
            }

        // ---- online softmax, per-query = per-lane ----
        const bool domask = (u >= 2 * jj);
        float cr[2];
        #pragma unroll
        for (int i = 0; i < 2; ++i) {
            const int qg = q0 + wv * 32 + i * 16 + n;    // this lane's query
            #pragma unroll
            for (int ct = 0; ct < 4; ++ct) {
                const int kq = kb + ct * 16 + quad * 4;
                #pragma unroll
                for (int r = 0; r < 4; ++r) {
                    float s = sc[i][ct][r] * sfac;
                    if (domask) s = (kq + r <= qg) ? s : -INFINITY;
                    sc[i][ct][r] = s;
                }
            }
            // in-lane max over 16 values
            float mx = -INFINITY;
            #pragma unroll
            for (int ct = 0; ct < 4; ++ct) {
                float a = fmaxf(fmaxf(sc[i][ct][0], sc[i][ct][1]),
                                fmaxf(sc[i][ct][2], sc[i][ct][3]));
                mx = fmaxf(mx, a);
            }
            mx = fmaxf(mx, __shfl_xor(mx, 16));
            mx = fmaxf(mx, __shfl_xor(mx, 32));
            const float mn = fmaxf(mrun[i], mx);
            const float c_ = exp2f(mrun[i] - mn);
            float rs = 0.f;
            #pragma unroll
            for (int ct = 0; ct < 4; ++ct) {
                #pragma unroll
                for (int r = 0; r < 4; ++r) {
                    const float p = exp2f(sc[i][ct][r] - mn);
                    sc[i][ct][r] = p;
                    rs += p;
                }
            }
            rs += __shfl_xor(rs, 16);
            rs += __shfl_xor(rs, 32);
            lrun[i] = lrun[i] * c_ + rs;
            mrun[i] = mn;
            cr[i] = c_;
        }
        #pragma unroll
        for (int i = 0; i < 2; ++i)
            #pragma unroll
            for (int dt = 0; dt < 4; ++dt)
                #pragma unroll
                for (int r = 0; r < 4; ++r) O[i][dt][r] *= cr[i];

        // ---- P^T -> per-wave LDS [q][key] -> B-frags ----
        #pragma unroll
        for (int i = 0; i < 2; ++i)
            #pragma unroll
            for (int ct = 0; ct < 4; ++ct) {
                bf16x4 pk;
                pk[0] = (short)f2bf(sc[i][ct][0]);
                pk[1] = (short)f2bf(sc[i][ct][1]);
                pk[2] = (short)f2bf(sc[i][ct][2]);
                pk[3] = (short)f2bf(sc[i][ct][3]);
                *(bf16x4*)&Ps[wv][i * 16 + n][ct * 16 + quad * 4] = pk;
            }
        bf16x8 pb[2][2];
        #pragma unroll
        for (int i = 0; i < 2; ++i) {
            pb[i][0] = *(const bf16x8*)&Ps[wv][i * 16 + n][quad * 8];
            pb[i][1] = *(const bf16x8*)&Ps[wv][i * 16 + n][32 + quad * 8];
        }

        // ---- O^T += V^T @ P^T ----
        #pragma unroll
        for (int dt = 0; dt < 4; ++dt) {
            const bf16x8 av0 = *(const bf16x8*)&Vs[cur][dt * 16 + n][quad * 8];
            const bf16x8 av1 = *(const bf16x8*)&Vs[cur][dt * 16 + n][32 + quad * 8];
            #pragma unroll
            for (int i = 0; i < 2; ++i) {
                O[i][dt] = __builtin_amdgcn_mfma_f32_16x16x32_bf16(av0, pb[i][0], O[i][dt], 0, 0, 0);
                O[i][dt] = __builtin_amdgcn_mfma_f32_16x16x32_bf16(av1, pb[i][1], O[i][dt], 0, 0, 0);
            }
        }

        if (u + 1 < ntiles) {
            const int nb = cur ^ 1;
            *(u32x4*)&Ks[nb][srow][sc8]      = kr0;
            *(u32x4*)&Ks[nb][32 + srow][sc8] = kr1;
            *(u32x4*)&Vs[nb][srow][sc8]      = vr0;
            *(u32x4*)&Vs[nb][32 + srow][sc8] = vr1;
        }
    }

    // ---- epilogue: normalize, transpose O^T via LDS, coalesced store ----
    #pragma unroll
    for (int i = 0; i < 2; ++i) {
        const float inv = 1.0f / lrun[i];
        #pragma unroll
        for (int dt = 0; dt < 4; ++dt) {
            bf16x4 pk;
            pk[0] = (short)f2bf(O[i][dt][0] * inv);
            pk[1] = (short)f2bf(O[i][dt][1] * inv);
            pk[2] = (short)f2bf(O[i][dt][2] * inv);
            pk[3] = (short)f2bf(O[i][dt][3] * inv);
            *(bf16x4*)&Ps[wv][i * 16 + n][dt * 16 + quad * 4] = pk;
        }
    }
    const int fr = lane >> 3;
    const int c8 = (lane & 7) * 8;
    #pragma unroll
    for (int it = 0; it < 4; ++it) {
        const int row = it * 8 + fr;                     // 0..31
        const int q   = q0 + wv * 32 + row;
        unsigned short* op = ot + ((long)(b * S_ + q) * H_ + h) * DK_ + c8;
        *(bf16x8*)op = *(const bf16x8*)&Ps[wv][row][c8];
    }
}

// ---------------------------------------------------------------------------
// Output projection: out[4096,1024] fp32 = ob @ WoT^T + bo. 128x64, BK=32.
// ---------------------------------------------------------------------------
__global__ __launch_bounds__(256) void oproj_gemm_kernel(
    const unsigned short* __restrict__ A,
    const unsigned short* __restrict__ Bt,
    const float* __restrict__ bias,
    float* __restrict__ out)
{
    const int K = 1024, N = 1024;
    __shared__ unsigned short As[128][40];
    __shared__ unsigned short Bs[64][40];

    const int t  = threadIdx.x;
    const int m0 = blockIdx.x * 128;
    const int n0 = blockIdx.y * 64;

    const int w    = t >> 6;
    const int lane = t & 63;
    const int n    = lane & 15;
    const int quad = lane >> 4;
    const int wm   = (w >> 1) * 64;
    const int wn   = (w & 1) * 32;

    const int lr = t >> 2;
    const int lc = (t & 3) * 8;

    f32x4 acc[4][2];
    #pragma unroll
    for (int i = 0; i < 4; ++i)
        #pragma unroll
        for (int j = 0; j < 2; ++j) acc[i][j] = 0.0f;

    u32x4 ar0 = *(const u32x4*)&A [(long)(m0 + lr)      * K + lc];
    u32x4 ar1 = *(const u32x4*)&A [(long)(m0 + 64 + lr) * K + lc];
    u32x4 br0 = *(const u32x4*)&Bt[(long)(n0 + lr)      * K + lc];

    for (int k0 = 0; k0 < K; k0 += 32) {
        __syncthreads();
        *(u32x4*)&As[lr][lc]      = ar0;
        *(u32x4*)&As[lr + 64][lc] = ar1;
        if (lr < 64) *(u32x4*)&Bs[lr][lc] = br0;
        __syncthreads();

        if (k0 + 32 < K) {
            ar0 = *(const u32x4*)&A [(long)(m0 + lr)      * K + k0 + 32 + lc];
            ar1 = *(const u32x4*)&A [(long)(m0 + 64 + lr) * K + k0 + 32 + lc];
            br0 = *(const u32x4*)&Bt[(long)(n0 + lr)      * K + k0 + 32 + lc];
        }

        bf16x8 af[4], bfr[2];
        #pragma unroll
        for (int i = 0; i < 4; ++i)
            af[i] = *(const bf16x8*)&As[wm + i * 16 + n][quad * 8];
        #pragma unroll
        for (int j = 0; j < 2; ++j)
            bfr[j] = *(const bf16x8*)&Bs[wn + j * 16 + n][quad * 8];
        #pragma unroll
        for (int mi = 0; mi < 4; ++mi)
            #pragma unroll
            for (int ni = 0; ni < 2; ++ni)
                acc[mi][ni] = __builtin_amdgcn_mfma_f32_16x16x32_bf16(
                    af[mi], bfr[ni], acc[mi][ni], 0, 0, 0);
    }

    #pragma unroll
    for (int mi = 0; mi < 4; ++mi) {
        #pragma unroll
        for (int r = 0; r < 4; ++r) {
            const int gm = m0 + wm + mi * 16 + quad * 4 + r;
            #pragma unroll
            for (int ni = 0; ni < 2; ++ni) {
                const int gn = n0 + wn + ni * 16 + n;
                out[(long)gm * N + gn] = acc[mi][ni][r] + bias[gn];
            }
        }
    }
}

// ---------------------------------------------------------------------------
extern "C" void kernel_launch(void* const* d_in, const int* in_sizes, int n_in,
                              void* d_out, int out_size, void* d_ws, size_t ws_size,
                              hipStream_t stream)
{
    const float* x  = (const float*)d_in[0];
    const float* Wq = (const float*)d_in[2];
    const float* bq = (const float*)d_in[3];
    const float* Wk = (const float*)d_in[4];
    const float* bk = (const float*)d_in[5];
    const float* Wv = (const float*)d_in[6];
    const float* bv = (const float*)d_in[7];
    const float* Wo = (const float*)d_in[8];
    const float* bo = (const float*)d_in[9];
    float* out = (float*)d_out;

    // Workspace (bf16 shorts), ~38.8 MB. ob aliases qkvm.
    unsigned short* ws    = (unsigned short*)d_ws;
    unsigned short* xb    = ws;                   // 4194304
    unsigned short* qkvm  = xb + 4194304;         // 6291456  [4096,1536]
    unsigned short* qbuf  = qkvm + 6291456;       // 4194304
    unsigned short* kbuf  = qbuf + 4194304;       // 1048576
    unsigned short* vbuf  = kbuf + 1048576;       // 1048576
    unsigned short* WqkvT = vbuf + 1048576;       // 1572864
    unsigned short* WoT   = WqkvT + 1572864;      // 1048576
    unsigned short* ob    = qkvm;                 // alias

    const int M = B_ * S_;                        // 4096

    cast_bf16_kernel<<<(M * D_ / 8) / 256, 256, 0, stream>>>(x, xb, M * D_ / 8);
    transpose_cast_kernel<<<256, 256, 0, stream>>>(Wq, WqkvT,                1024, 1024);
    transpose_cast_kernel<<<64,  256, 0, stream>>>(Wk, WqkvT + 1024 * 1024, 1024, 256);
    transpose_cast_kernel<<<64,  256, 0, stream>>>(Wv, WqkvT + 1280 * 1024, 1024, 256);
    transpose_cast_kernel<<<256, 256, 0, stream>>>(Wo, WoT,                 1024, 1024);

    qkv_gemm_kernel<<<dim3(32, 12), 256, 0, stream>>>(xb, WqkvT, bq, bk, bv, qkvm);
    rope_scatter_kernel<<<(M * 80) / 256, 256, 0, stream>>>(qkvm, qbuf, kbuf);
    vT_kernel<<<B_ * KH_ * (S_ / 64), 256, 0, stream>>>(qkvm, vbuf);

    attn_kernel<<<B_ * H_ * (S_ / 128), 256, 0, stream>>>(qbuf, kbuf, vbuf, ob);

    oproj_gemm_kernel<<<dim3(32, 16), 256, 0, stream>>>(ob, WoT, bo, out);
}

// Round 8
// 217.934 us; speedup vs baseline: 6.2930x; 1.2700x over previous
//
#include <hip/hip_runtime.h>
#include <math.h>

#define B_   2
#define S_   2048
#define D_   1024
#define H_   16
#define KH_  4
#define DK_  64

using bf16x8 = __attribute__((ext_vector_type(8))) short;
using bf16x4 = __attribute__((ext_vector_type(4))) short;
using f32x4  = __attribute__((ext_vector_type(4))) float;
using u32x4  = __attribute__((ext_vector_type(4))) unsigned int;

__device__ inline unsigned short f2bf(float f) {
    unsigned u = __float_as_uint(f);
    u += 0x7FFFu + ((u >> 16) & 1u);          // RNE
    return (unsigned short)(u >> 16);
}
__device__ inline float bf2f(unsigned short u) {
    return __uint_as_float(((unsigned)u) << 16);
}

// ---------------------------------------------------------------------------
// cast fp32 -> bf16, 8 elems/thread
// ---------------------------------------------------------------------------
__global__ __launch_bounds__(256) void cast_bf16_kernel(
    const float* __restrict__ in, unsigned short* __restrict__ out, int n8)
{
    const int i = blockIdx.x * 256 + threadIdx.x;
    if (i >= n8) return;
    f32x4 a = *(const f32x4*)(in + (long)i * 8);
    f32x4 b = *(const f32x4*)(in + (long)i * 8 + 4);
    bf16x8 o;
    o[0] = (short)f2bf(a[0]); o[1] = (short)f2bf(a[1]);
    o[2] = (short)f2bf(a[2]); o[3] = (short)f2bf(a[3]);
    o[4] = (short)f2bf(b[0]); o[5] = (short)f2bf(b[1]);
    o[6] = (short)f2bf(b[2]); o[7] = (short)f2bf(b[3]);
    *(bf16x8*)(out + (long)i * 8) = o;
}

// ---------------------------------------------------------------------------
// transpose + cast: in fp32 (R,C) -> out bf16 (C,R). 64x64 tiles.
// ---------------------------------------------------------------------------
__global__ __launch_bounds__(256) void transpose_cast_kernel(
    const float* __restrict__ in, unsigned short* __restrict__ out, int R, int C)
{
    __shared__ float T[64][65];
    const int bx = blockIdx.x;
    const int nr = R >> 6;
    const int r0 = (bx % nr) * 64;
    const int c0 = (bx / nr) * 64;
    const int t  = threadIdx.x;

    {
        const int r  = t >> 2;
        const int cq = (t & 3) * 16;
        const float* src = in + (long)(r0 + r) * C + c0 + cq;
        #pragma unroll
        for (int i = 0; i < 4; ++i) {
            f32x4 v = *(const f32x4*)(src + i * 4);
            T[r][cq + i * 4 + 0] = v[0];
            T[r][cq + i * 4 + 1] = v[1];
            T[r][cq + i * 4 + 2] = v[2];
            T[r][cq + i * 4 + 3] = v[3];
        }
    }
    __syncthreads();
    {
        const int c  = t >> 2;
        const int rq = (t & 3) * 16;
        bf16x8 p0, p1;
        #pragma unroll
        for (int i = 0; i < 8; ++i) {
            p0[i] = (short)f2bf(T[rq + i][c]);
            p1[i] = (short)f2bf(T[rq + 8 + i][c]);
        }
        unsigned short* dst = out + (long)(c0 + c) * R + r0 + rq;
        *(bf16x8*)dst       = p0;
        *(bf16x8*)(dst + 8) = p1;
    }
}

// ---------------------------------------------------------------------------
// QKV GEMM: qkvm[4096,1536] = xb @ WqkvT^T + bias, bf16 out, row-major.
// 128x128 tile, BK=32, 4 waves (2x2), register-prefetch pipeline.
// ---------------------------------------------------------------------------
__global__ __launch_bounds__(256) void qkv_gemm_kernel(
    const unsigned short* __restrict__ A,     // [4096,1024]
    const unsigned short* __restrict__ Bt,    // [1536,1024]
    const float* __restrict__ bq,
    const float* __restrict__ bk,
    const float* __restrict__ bv,
    unsigned short* __restrict__ out)         // [4096,1536] bf16
{
    const int K = 1024, N = 1536;
    __shared__ unsigned short As[128][40];
    __shared__ unsigned short Bs[128][40];

    const int t  = threadIdx.x;
    const int m0 = blockIdx.x * 128;
    const int n0 = blockIdx.y * 128;

    const int w    = t >> 6;
    const int lane = t & 63;
    const int n    = lane & 15;
    const int quad = lane >> 4;
    const int wm   = (w >> 1) * 64;
    const int wn   = (w & 1) * 64;

    const int lr = t >> 2;
    const int lc = (t & 3) * 8;

    f32x4 acc[4][4];
    #pragma unroll
    for (int i = 0; i < 4; ++i)
        #pragma unroll
        for (int j = 0; j < 4; ++j) acc[i][j] = 0.0f;

    u32x4 ar0 = *(const u32x4*)&A [(long)(m0 + lr)      * K + lc];
    u32x4 ar1 = *(const u32x4*)&A [(long)(m0 + 64 + lr) * K + lc];
    u32x4 br0 = *(const u32x4*)&Bt[(long)(n0 + lr)      * K + lc];
    u32x4 br1 = *(const u32x4*)&Bt[(long)(n0 + 64 + lr) * K + lc];

    for (int k0 = 0; k0 < K; k0 += 32) {
        __syncthreads();
        *(u32x4*)&As[lr][lc]      = ar0;
        *(u32x4*)&As[lr + 64][lc] = ar1;
        *(u32x4*)&Bs[lr][lc]      = br0;
        *(u32x4*)&Bs[lr + 64][lc] = br1;
        __syncthreads();

        if (k0 + 32 < K) {
            ar0 = *(const u32x4*)&A [(long)(m0 + lr)      * K + k0 + 32 + lc];
            ar1 = *(const u32x4*)&A [(long)(m0 + 64 + lr) * K + k0 + 32 + lc];
            br0 = *(const u32x4*)&Bt[(long)(n0 + lr)      * K + k0 + 32 + lc];
            br1 = *(const u32x4*)&Bt[(long)(n0 + 64 + lr) * K + k0 + 32 + lc];
        }

        bf16x8 af[4], bfr[4];
        #pragma unroll
        for (int i = 0; i < 4; ++i) {
            af[i]  = *(const bf16x8*)&As[wm + i * 16 + n][quad * 8];
            bfr[i] = *(const bf16x8*)&Bs[wn + i * 16 + n][quad * 8];
        }
        #pragma unroll
        for (int mi = 0; mi < 4; ++mi)
            #pragma unroll
            for (int ni = 0; ni < 4; ++ni)
                acc[mi][ni] = __builtin_amdgcn_mfma_f32_16x16x32_bf16(
                    af[mi], bfr[ni], acc[mi][ni], 0, 0, 0);
    }

    #pragma unroll
    for (int mi = 0; mi < 4; ++mi) {
        #pragma unroll
        for (int r = 0; r < 4; ++r) {
            const int gm = m0 + wm + mi * 16 + quad * 4 + r;
            #pragma unroll
            for (int ni = 0; ni < 4; ++ni) {
                const int gn = n0 + wn + ni * 16 + n;
                const float b = (gn < 1024) ? bq[gn]
                              : (gn < 1280) ? bk[gn - 1024]
                                            : bv[gn - 1280];
                out[(long)gm * N + gn] = f2bf(acc[mi][ni][r] + b);
            }
        }
    }
}

// ---------------------------------------------------------------------------
// RoPE scatter: qkvm rows -> qbuf (B,H,S,DK) and kbuf (B,KH,S,DK), bf16.
// ---------------------------------------------------------------------------
__global__ __launch_bounds__(256) void rope_scatter_kernel(
    const unsigned short* __restrict__ qkvm,  // [4096,1536]
    unsigned short* __restrict__ qbuf,
    unsigned short* __restrict__ kbuf)
{
    const int idx = blockIdx.x * 256 + threadIdx.x;   // 4096*80 total
    const int m   = idx / 80;
    const int rem = idx - m * 80;
    const int h20 = rem >> 2;
    const int d0  = (rem & 3) * 8;

    const int s  = m & (S_ - 1);
    const int bb = m >> 11;
    const int col0 = (h20 < 16) ? h20 * 64 + d0 : 1024 + (h20 - 16) * 64 + d0;

    const bf16x8 x1v = *(const bf16x8*)(qkvm + (long)m * 1536 + col0);
    const bf16x8 x2v = *(const bf16x8*)(qkvm + (long)m * 1536 + col0 + 32);
    bf16x8 o1, o2;
    #pragma unroll
    for (int j = 0; j < 8; ++j) {
        const int d = d0 + j;
        const float theta = exp2f(-(float)d * (13.287712379549449f / 32.0f));
        const float f = (float)s * theta;
        const float c = cosf(f), sn = sinf(f);
        const float x1 = bf2f((unsigned short)x1v[j]);
        const float x2 = bf2f((unsigned short)x2v[j]);
        o1[j] = (short)f2bf(x1 * c - x2 * sn);
        o2[j] = (short)f2bf(x2 * c + x1 * sn);
    }
    unsigned short* dst = (h20 < 16)
        ? qbuf + ((long)(bb * H_ + h20) * S_ + s) * DK_ + d0
        : kbuf + ((long)(bb * KH_ + (h20 - 16)) * S_ + s) * DK_ + d0;
    *(bf16x8*)dst        = o1;
    *(bf16x8*)(dst + 32) = o2;
}

// ---------------------------------------------------------------------------
// V transpose: qkvm cols 1280..1535 -> vbuf (B,KH,DK,S) bf16. 64x64 tiles.
// ---------------------------------------------------------------------------
__global__ __launch_bounds__(256) void vT_kernel(
    const unsigned short* __restrict__ qkvm,
    unsigned short* __restrict__ vbuf)
{
    __shared__ unsigned short T[64][72];
    const int bx  = blockIdx.x;
    const int bkh = bx >> 5;
    const int s0  = (bx & 31) * 64;
    const int t   = threadIdx.x;

    {
        const int s  = t >> 2;
        const int dq = (t & 3) * 16;
        const unsigned short* src =
            qkvm + (long)((bkh >> 2) * S_ + s0 + s) * 1536 + 1280 + (bkh & 3) * 64 + dq;
        *(bf16x8*)&T[s][dq]     = *(const bf16x8*)src;
        *(bf16x8*)&T[s][dq + 8] = *(const bf16x8*)(src + 8);
    }
    __syncthreads();
    {
        const int d  = t >> 2;
        const int sq = (t & 3) * 16;
        bf16x8 p0, p1;
        #pragma unroll
        for (int i = 0; i < 8; ++i) {
            p0[i] = (short)T[sq + i][d];
            p1[i] = (short)T[sq + 8 + i][d];
        }
        unsigned short* dst = vbuf + ((long)bkh * DK_ + d) * S_ + s0 + sq;
        *(bf16x8*)dst       = p0;
        *(bf16x8*)(dst + 8) = p1;
    }
}

// ---------------------------------------------------------------------------
// bf16 MFMA causal flash attention, v4.
// One 64-query tile per block (4 waves x 16 q), grid = B*H*32 = 1024 blocks,
// HEAVY-FIRST dispatch order (LPT backfill balances CUs without co-residency
// assumptions - round-7 pairing failed, occupancy 7.8% tail).
// Transposed scores (S^T = K@Q^T), lane-owned query column, 2-shuffle
// reductions. LDS 41.5 KB -> 3 blocks/CU resident.
// ---------------------------------------------------------------------------
__global__ __launch_bounds__(256) void attn_kernel(
    const unsigned short* __restrict__ qb,   // (B,H,S,DK)
    const unsigned short* __restrict__ kbf,  // (B,KH,S,DK)
    const unsigned short* __restrict__ vT,   // (B,KH,DK,S)
    unsigned short* __restrict__ ot)         // (B,S,H*DK)
{
    __shared__ unsigned short Ks[2][64][72];
    __shared__ unsigned short Vs[2][64][72];
    __shared__ unsigned short Ps[4][16][72];

    const int tid = threadIdx.x;
    const int bx  = blockIdx.x;
    const int qt  = 31 - (bx >> 5);          // heavy blocks dispatch first
    const int bh  = bx & 31;
    const int b   = bh >> 4, h = bh & 15;
    const int kh  = h >> 2;
    const int q0  = qt * 64;

    const int wv   = tid >> 6;
    const int lane = tid & 63;
    const int n    = lane & 15;
    const int quad = lane >> 4;

    // Q fragments (B-operand): lane n -> query q0 + wv*16 + n
    const unsigned short* qp =
        qb + ((long)(b * H_ + h) * S_ + q0 + wv * 16 + n) * DK_;
    const bf16x8 qa0 = *(const bf16x8*)(qp + quad * 8);
    const bf16x8 qa1 = *(const bf16x8*)(qp + 32 + quad * 8);

    f32x4 O[4];                       // O^T[d = dt*16+quad*4+r][q = n]
    #pragma unroll
    for (int dt = 0; dt < 4; ++dt) O[dt] = 0.0f;
    float mrun = -INFINITY, lrun = 0.f;

    const unsigned short* kbase = kbf + (long)(b * KH_ + kh) * S_ * DK_;
    const unsigned short* vbase = vT  + (long)(b * KH_ + kh) * DK_ * S_;

    const int ntiles = qt + 1;
    const int srow = tid >> 3;
    const int sc8  = (tid & 7) * 8;

    u32x4 kr0 = *(const u32x4*)(kbase + (long)srow * DK_ + sc8);
    u32x4 kr1 = *(const u32x4*)(kbase + (long)(32 + srow) * DK_ + sc8);
    u32x4 vr0 = *(const u32x4*)(vbase + (long)srow * S_ + sc8);
    u32x4 vr1 = *(const u32x4*)(vbase + (long)(32 + srow) * S_ + sc8);
    *(u32x4*)&Ks[0][srow][sc8]      = kr0;
    *(u32x4*)&Ks[0][32 + srow][sc8] = kr1;
    *(u32x4*)&Vs[0][srow][sc8]      = vr0;
    *(u32x4*)&Vs[0][32 + srow][sc8] = vr1;

    const float sfac = 0.125f * 1.44269504f;   // 1/sqrt(64) * log2(e)

    for (int u = 0; u < ntiles; ++u) {
        const int cur = u & 1;
        const int kb  = u * 64;
        __syncthreads();

        if (u + 1 < ntiles) {
            const int kbn = kb + 64;
            kr0 = *(const u32x4*)(kbase + (long)(kbn + srow) * DK_ + sc8);
            kr1 = *(const u32x4*)(kbase + (long)(kbn + 32 + srow) * DK_ + sc8);
            vr0 = *(const u32x4*)(vbase + (long)srow * S_ + kbn + sc8);
            vr1 = *(const u32x4*)(vbase + (long)(32 + srow) * S_ + kbn + sc8);
        }

        // ---- S^T = K @ Q^T : C[key][query], query = lane col n ----
        f32x4 sc[4];
        #pragma unroll
        for (int ct = 0; ct < 4; ++ct) {
            const bf16x8 kf0 = *(const bf16x8*)&Ks[cur][ct * 16 + n][quad * 8];
            const bf16x8 kf1 = *(const bf16x8*)&Ks[cur][ct * 16 + n][32 + quad * 8];
            f32x4 c = 0.0f;
            c = __builtin_amdgcn_mfma_f32_16x16x32_bf16(kf0, qa0, c, 0, 0, 0);
            c = __builtin_amdgcn_mfma_f32_16x16x32_bf16(kf1, qa1, c, 0, 0, 0);
            sc[ct] = c;
        }

        // ---- online softmax, one query per lane ----
        const bool domask = (u == qt);        // only the diagonal tile
        const int qg = q0 + wv * 16 + n;
        #pragma unroll
        for (int ct = 0; ct < 4; ++ct) {
            const int kq = kb + ct * 16 + quad * 4;
            #pragma unroll
            for (int r = 0; r < 4; ++r) {
                float s = sc[ct][r] * sfac;
                if (domask) s = (kq + r <= qg) ? s : -INFINITY;
                sc[ct][r] = s;
            }
        }
        float mx = -INFINITY;
        #pragma unroll
        for (int ct = 0; ct < 4; ++ct)
            mx = fmaxf(mx, fmaxf(fmaxf(sc[ct][0], sc[ct][1]),
                                 fmaxf(sc[ct][2], sc[ct][3])));
        mx = fmaxf(mx, __shfl_xor(mx, 16));
        mx = fmaxf(mx, __shfl_xor(mx, 32));
        const float mn = fmaxf(mrun, mx);
        const float c_ = exp2f(mrun - mn);
        float rs = 0.f;
        #pragma unroll
        for (int ct = 0; ct < 4; ++ct) {
            #pragma unroll
            for (int r = 0; r < 4; ++r) {
                const float p = exp2f(sc[ct][r] - mn);
                sc[ct][r] = p;
                rs += p;
            }
        }
        rs += __shfl_xor(rs, 16);
        rs += __shfl_xor(rs, 32);
        lrun = lrun * c_ + rs;
        mrun = mn;
        #pragma unroll
        for (int dt = 0; dt < 4; ++dt)
            #pragma unroll
            for (int r = 0; r < 4; ++r) O[dt][r] *= c_;

        // ---- P^T -> per-wave LDS [q][key] -> B-frags ----
        #pragma unroll
        for (int ct = 0; ct < 4; ++ct) {
            bf16x4 pk;
            pk[0] = (short)f2bf(sc[ct][0]);
            pk[1] = (short)f2bf(sc[ct][1]);
            pk[2] = (short)f2bf(sc[ct][2]);
            pk[3] = (short)f2bf(sc[ct][3]);
            *(bf16x4*)&Ps[wv][n][ct * 16 + quad * 4] = pk;
        }
        const bf16x8 pb0 = *(const bf16x8*)&Ps[wv][n][quad * 8];
        const bf16x8 pb1 = *(const bf16x8*)&Ps[wv][n][32 + quad * 8];

        // ---- O^T += V^T @ P^T ----
        #pragma unroll
        for (int dt = 0; dt < 4; ++dt) {
            const bf16x8 av0 = *(const bf16x8*)&Vs[cur][dt * 16 + n][quad * 8];
            const bf16x8 av1 = *(const bf16x8*)&Vs[cur][dt * 16 + n][32 + quad * 8];
            O[dt] = __builtin_amdgcn_mfma_f32_16x16x32_bf16(av0, pb0, O[dt], 0, 0, 0);
            O[dt] = __builtin_amdgcn_mfma_f32_16x16x32_bf16(av1, pb1, O[dt], 0, 0, 0);
        }

        if (u + 1 < ntiles) {
            const int nb = cur ^ 1;
            *(u32x4*)&Ks[nb][srow][sc8]      = kr0;
            *(u32x4*)&Ks[nb][32 + srow][sc8] = kr1;
            *(u32x4*)&Vs[nb][srow][sc8]      = vr0;
            *(u32x4*)&Vs[nb][32 + srow][sc8] = vr1;
        }
    }

    // ---- epilogue: normalize, transpose O^T via per-wave LDS, store ----
    const float inv = 1.0f / lrun;
    #pragma unroll
    for (int dt = 0; dt < 4; ++dt) {
        bf16x4 pk;
        pk[0] = (short)f2bf(O[dt][0] * inv);
        pk[1] = (short)f2bf(O[dt][1] * inv);
        pk[2] = (short)f2bf(O[dt][2] * inv);
        pk[3] = (short)f2bf(O[dt][3] * inv);
        *(bf16x4*)&Ps[wv][n][dt * 16 + quad * 4] = pk;
    }
    const int fr = lane >> 3;
    const int c8 = (lane & 7) * 8;
    #pragma unroll
    for (int it = 0; it < 2; ++it) {
        const int row = it * 8 + fr;                     // 0..15
        const int q   = q0 + wv * 16 + row;
        unsigned short* op = ot + ((long)(b * S_ + q) * H_ + h) * DK_ + c8;
        *(bf16x8*)op = *(const bf16x8*)&Ps[wv][row][c8];
    }
}

// ---------------------------------------------------------------------------
// Output projection: out[4096,1024] fp32 = ob @ WoT^T + bo. 128x64, BK=32.
// ---------------------------------------------------------------------------
__global__ __launch_bounds__(256) void oproj_gemm_kernel(
    const unsigned short* __restrict__ A,
    const unsigned short* __restrict__ Bt,
    const float* __restrict__ bias,
    float* __restrict__ out)
{
    const int K = 1024, N = 1024;
    __shared__ unsigned short As[128][40];
    __shared__ unsigned short Bs[64][40];

    const int t  = threadIdx.x;
    const int m0 = blockIdx.x * 128;
    const int n0 = blockIdx.y * 64;

    const int w    = t >> 6;
    const int lane = t & 63;
    const int n    = lane & 15;
    const int quad = lane >> 4;
    const int wm   = (w >> 1) * 64;
    const int wn   = (w & 1) * 32;

    const int lr = t >> 2;
    const int lc = (t & 3) * 8;

    f32x4 acc[4][2];
    #pragma unroll
    for (int i = 0; i < 4; ++i)
        #pragma unroll
        for (int j = 0; j < 2; ++j) acc[i][j] = 0.0f;

    u32x4 ar0 = *(const u32x4*)&A [(long)(m0 + lr)      * K + lc];
    u32x4 ar1 = *(const u32x4*)&A [(long)(m0 + 64 + lr) * K + lc];
    u32x4 br0 = *(const u32x4*)&Bt[(long)(n0 + lr)      * K + lc];

    for (int k0 = 0; k0 < K; k0 += 32) {
        __syncthreads();
        *(u32x4*)&As[lr][lc]      = ar0;
        *(u32x4*)&As[lr + 64][lc] = ar1;
        if (lr < 64) *(u32x4*)&Bs[lr][lc] = br0;
        __syncthreads();

        if (k0 + 32 < K) {
            ar0 = *(const u32x4*)&A [(long)(m0 + lr)      * K + k0 + 32 + lc];
            ar1 = *(const u32x4*)&A [(long)(m0 + 64 + lr) * K + k0 + 32 + lc];
            br0 = *(const u32x4*)&Bt[(long)(n0 + lr)      * K + k0 + 32 + lc];
        }

        bf16x8 af[4], bfr[2];
        #pragma unroll
        for (int i = 0; i < 4; ++i)
            af[i] = *(const bf16x8*)&As[wm + i * 16 + n][quad * 8];
        #pragma unroll
        for (int j = 0; j < 2; ++j)
            bfr[j] = *(const bf16x8*)&Bs[wn + j * 16 + n][quad * 8];
        #pragma unroll
        for (int mi = 0; mi < 4; ++mi)
            #pragma unroll
            for (int ni = 0; ni < 2; ++ni)
                acc[mi][ni] = __builtin_amdgcn_mfma_f32_16x16x32_bf16(
                    af[mi], bfr[ni], acc[mi][ni], 0, 0, 0);
    }

    #pragma unroll
    for (int mi = 0; mi < 4; ++mi) {
        #pragma unroll
        for (int r = 0; r < 4; ++r) {
            const int gm = m0 + wm + mi * 16 + quad * 4 + r;
            #pragma unroll
            for (int ni = 0; ni < 2; ++ni) {
                const int gn = n0 + wn + ni * 16 + n;
                out[(long)gm * N + gn] = acc[mi][ni][r] + bias[gn];
            }
        }
    }
}

// ---------------------------------------------------------------------------
extern "C" void kernel_launch(void* const* d_in, const int* in_sizes, int n_in,
                              void* d_out, int out_size, void* d_ws, size_t ws_size,
                              hipStream_t stream)
{
    const float* x  = (const float*)d_in[0];
    const float* Wq = (const float*)d_in[2];
    const float* bq = (const float*)d_in[3];
    const float* Wk = (const float*)d_in[4];
    const float* bk = (const float*)d_in[5];
    const float* Wv = (const float*)d_in[6];
    const float* bv = (const float*)d_in[7];
    const float* Wo = (const float*)d_in[8];
    const float* bo = (const float*)d_in[9];
    float* out = (float*)d_out;

    // Workspace (bf16 shorts), ~38.8 MB. ob aliases qkvm.
    unsigned short* ws    = (unsigned short*)d_ws;
    unsigned short* xb    = ws;                   // 4194304
    unsigned short* qkvm  = xb + 4194304;         // 6291456  [4096,1536]
    unsigned short* qbuf  = qkvm + 6291456;       // 4194304
    unsigned short* kbuf  = qbuf + 4194304;       // 1048576
    unsigned short* vbuf  = kbuf + 1048576;       // 1048576
    unsigned short* WqkvT = vbuf + 1048576;       // 1572864
    unsigned short* WoT   = WqkvT + 1572864;      // 1048576
    unsigned short* ob    = qkvm;                 // alias

    const int M = B_ * S_;                        // 4096

    cast_bf16_kernel<<<(M * D_ / 8) / 256, 256, 0, stream>>>(x, xb, M * D_ / 8);
    transpose_cast_kernel<<<256, 256, 0, stream>>>(Wq, WqkvT,                1024, 1024);
    transpose_cast_kernel<<<64,  256, 0, stream>>>(Wk, WqkvT + 1024 * 1024, 1024, 256);
    transpose_cast_kernel<<<64,  256, 0, stream>>>(Wv, WqkvT + 1280 * 1024, 1024, 256);
    transpose_cast_kernel<<<256, 256, 0, stream>>>(Wo, WoT,                 1024, 1024);

    qkv_gemm_kernel<<<dim3(32, 12), 256, 0, stream>>>(xb, WqkvT, bq, bk, bv, qkvm);
    rope_scatter_kernel<<<(M * 80) / 256, 256, 0, stream>>>(qkvm, qbuf, kbuf);
    vT_kernel<<<B_ * KH_ * (S_ / 64), 256, 0, stream>>>(qkvm, vbuf);

    attn_kernel<<<B_ * H_ * (S_ / 64), 256, 0, stream>>>(qbuf, kbuf, vbuf, ob);

    oproj_gemm_kernel<<<dim3(32, 16), 256, 0, stream>>>(ob, WoT, bo, out);
}